// Round 4
// baseline (2380.745 us; speedup 1.0000x reference)
//
#include <hip/hip_runtime.h>

typedef unsigned int u32;
typedef unsigned long long u64;
typedef unsigned short ushort_t;

#define NB 16
#define NPT 4096
#define NS 1024
#define NK 32
#define ND 64
#define CNT_TOTAL 524288.0f   // 16*1024*32
#define OUT_NP_OFF 49152      // new_points offset in d_out (f32 elements)

// ---------------- FPS: one block per batch, exact f32 ops ----------------
__global__ __launch_bounds__(1024) void k_fps(const float* __restrict__ xyz,
                                              float* __restrict__ out_xyz) {
  __shared__ float sx[NPT], sy[NPT], sz[NPT];
  __shared__ u64 warr[16];
  const int b = blockIdx.x, t = threadIdx.x;
  const float* xb = xyz + (size_t)b * NPT * 3;
  for (int n = t; n < NPT; n += 1024) {
    sx[n] = xb[3*n+0]; sy[n] = xb[3*n+1]; sz[n] = xb[3*n+2];
  }
  float dst0 = 1e10f, dst1 = 1e10f, dst2 = 1e10f, dst3 = 1e10f;
  __syncthreads();
  int f = 0;
  float* ob = out_xyz + (size_t)b * NS * 3;
  for (int it = 0; it < NS; ++it) {
    if (t == 0) { ob[3*it+0] = sx[f]; ob[3*it+1] = sy[f]; ob[3*it+2] = sz[f]; }
    const float cx = sx[f], cy = sy[f], cz = sz[f];
    float bv = -1.0f; int bi = 0;
    // exact numpy order: ((dx*dx + dy*dy) + dz*dz), no FMA contraction
    {
      int n = t;
      float dx = __fsub_rn(sx[n],cx), dy = __fsub_rn(sy[n],cy), dz = __fsub_rn(sz[n],cz);
      float d = __fadd_rn(__fadd_rn(__fmul_rn(dx,dx), __fmul_rn(dy,dy)), __fmul_rn(dz,dz));
      d = fminf(dst0, d); dst0 = d; if (d > bv) { bv = d; bi = n; }
    }
    {
      int n = t + 1024;
      float dx = __fsub_rn(sx[n],cx), dy = __fsub_rn(sy[n],cy), dz = __fsub_rn(sz[n],cz);
      float d = __fadd_rn(__fadd_rn(__fmul_rn(dx,dx), __fmul_rn(dy,dy)), __fmul_rn(dz,dz));
      d = fminf(dst1, d); dst1 = d; if (d > bv) { bv = d; bi = n; }
    }
    {
      int n = t + 2048;
      float dx = __fsub_rn(sx[n],cx), dy = __fsub_rn(sy[n],cy), dz = __fsub_rn(sz[n],cz);
      float d = __fadd_rn(__fadd_rn(__fmul_rn(dx,dx), __fmul_rn(dy,dy)), __fmul_rn(dz,dz));
      d = fminf(dst2, d); dst2 = d; if (d > bv) { bv = d; bi = n; }
    }
    {
      int n = t + 3072;
      float dx = __fsub_rn(sx[n],cx), dy = __fsub_rn(sy[n],cy), dz = __fsub_rn(sz[n],cz);
      float d = __fadd_rn(__fadd_rn(__fmul_rn(dx,dx), __fmul_rn(dy,dy)), __fmul_rn(dz,dz));
      d = fminf(dst3, d); dst3 = d; if (d > bv) { bv = d; bi = n; }
    }
    // key: (value desc, index asc); dist >= 0 so float bits are monotone
    u64 best = ((u64)__float_as_uint(bv) << 32) | (u32)(NPT - 1 - bi);
    #pragma unroll
    for (int sft = 32; sft >= 1; sft >>= 1) {
      u64 o = __shfl_xor(best, sft, 64);
      if (o > best) best = o;
    }
    if ((t & 63) == 0) warr[t >> 6] = best;
    __syncthreads();
    u64 m = warr[0];
    #pragma unroll
    for (int i = 1; i < 16; ++i) { u64 o = warr[i]; if (o > m) m = o; }
    f = NPT - 1 - (int)(m & 0xffffffffu);   // always in [0, 4095]
    __syncthreads();
  }
}

// ---------------- Ball query: one wave per (b,s) pair ----------------
#define SQCAP 1024
__global__ __launch_bounds__(256) void k_ball(const float* __restrict__ xyz,
                                              const float* __restrict__ nxyz,
                                              ushort_t* __restrict__ ballidx) {
  __shared__ u64 keys[4][SQCAP];
  const int w = threadIdx.x >> 6, lane = threadIdx.x & 63;
  const int pair = blockIdx.x * 4 + w;
  const int b = pair >> 10;
  const float* xb = xyz + (size_t)b * NPT * 3;
  const float nx = nxyz[(size_t)pair*3+0];
  const float ny = nxyz[(size_t)pair*3+1];
  const float nz = nxyz[(size_t)pair*3+2];
  const float ssn = __fadd_rn(__fadd_rn(__fmul_rn(nx,nx), __fmul_rn(ny,ny)), __fmul_rn(nz,nz));
  int cnt = 0;
  for (int n0 = 0; n0 < NPT; n0 += 64) {
    const int n = n0 + lane;
    const float px = xb[3*n+0], py = xb[3*n+1], pz = xb[3*n+2];
    const float ssx = __fadd_rn(__fadd_rn(__fmul_rn(px,px), __fmul_rn(py,py)), __fmul_rn(pz,pz));
    const float dt  = __fadd_rn(__fadd_rn(__fmul_rn(nx,px), __fmul_rn(ny,py)), __fmul_rn(nz,pz));
    const float d   = __fsub_rn(__fadd_rn(ssn, ssx), __fmul_rn(2.0f, dt));
    const bool in = !(d > 0.04f);   // keep d <= radius^2 (f32(0.04) decision-equivalent, see notes)
    const u64 mask = __ballot(in);
    if (in) {
      int pos = cnt + (int)__popcll(mask & ((1ull << lane) - 1ull));
      if (pos < SQCAP) {
        u32 bits = __float_as_uint(d);
        u32 mapped = (bits & 0x80000000u) ? ~bits : (bits | 0x80000000u); // total order incl. negatives
        keys[w][pos] = ((u64)mapped << 32) | (u32)n;
      }
    }
    cnt += (int)__popcll(mask);
  }
  if (cnt > SQCAP) cnt = SQCAP;
  ushort_t* op = ballidx + (size_t)pair * NK;
  int first = 0;
  volatile u64* kp = &keys[w][0];
  for (int iter = 0; iter < NK; ++iter) {
    if (iter < cnt) {
      u64 mb = ~0ull;
      for (int i = lane; i < cnt; i += 64) { u64 kk = kp[i]; if (kk < mb) mb = kk; }
      #pragma unroll
      for (int sft = 32; sft >= 1; sft >>= 1) {
        u64 o = __shfl_xor(mb, sft, 64);
        if (o < mb) mb = o;
      }
      for (int i = lane; i < cnt; i += 64) { if (kp[i] == mb) kp[i] = ~0ull; }
      const int widx = (int)(mb & 0xffffffffu);
      if (iter == 0) first = widx;
      if (lane == 0) op[iter] = (ushort_t)widx;
    } else {
      if (lane == 0) op[iter] = (ushort_t)first;
    }
  }
}

// ================= shared helpers for conv passes (all f32) =================
template<int ROWS, int K, int LDW>
__device__ __forceinline__ void load_W(float* Ws, const float* __restrict__ W, int t) {
  for (int e = t; e < ROWS * K; e += 256) Ws[(e / K) * LDW + (e % K)] = W[e];
}

__device__ __forceinline__ void gather_X(float (*Xs)[69],
    const float* __restrict__ xyz, const float* __restrict__ points,
    const float* __restrict__ nxyz, const ushort_t* __restrict__ ballidx,
    int bp4, int b, int t) {
  if (t < 128) {
    const int pair = bp4 + (t >> 5);
    const int idx = (int)ballidx[pair * NK + (t & 31)];
    const float* p = xyz + ((size_t)b * NPT + idx) * 3;
    const float* nzp = nxyz + (size_t)pair * 3;
    Xs[t][0] = __fsub_rn(p[0], nzp[0]);
    Xs[t][1] = __fsub_rn(p[1], nzp[1]);
    Xs[t][2] = __fsub_rn(p[2], nzp[2]);
  }
  for (int g = t; g < 2048; g += 256) {
    const int r = g >> 4, ch = g & 15;
    const int pair = bp4 + (r >> 5);
    const int idx = (int)ballidx[pair * NK + (r & 31)];
    float4 v = *(const float4*)(points + ((size_t)b * NPT + idx) * ND + ch * 4);
    Xs[r][3 + ch*4 + 0] = v.x; Xs[r][3 + ch*4 + 1] = v.y;
    Xs[r][3 + ch*4 + 2] = v.z; Xs[r][3 + ch*4 + 3] = v.w;
  }
}

template<int K, int LDW>
__device__ __forceinline__ void gemm4(const float (*Xs)[69], const float* Ws,
                                      const float* __restrict__ bias, int biasOff,
                                      int tr, int tc, float acc[8][4]) {
  #pragma unroll
  for (int j = 0; j < 4; ++j) {
    float bb = bias[biasOff + tc*4 + j];
    #pragma unroll
    for (int i = 0; i < 8; ++i) acc[i][j] = bb;
  }
  for (int c = 0; c < K; ++c) {
    float wv[4];
    #pragma unroll
    for (int j = 0; j < 4; ++j) wv[j] = Ws[(tc*4 + j) * LDW + c];
    #pragma unroll
    for (int i = 0; i < 8; ++i) {
      float xv = Xs[tr*8 + i][c];
      #pragma unroll
      for (int j = 0; j < 4; ++j) acc[i][j] = fmaf(xv, wv[j], acc[i][j]);
    }
  }
}

__device__ __forceinline__ void bn_coef(const float* __restrict__ stats, int base,
    const float* __restrict__ g, const float* __restrict__ bt,
    float* sc, float* sh, int t) {
  if (t < 64) {
    const float inv = 1.0f / CNT_TOTAL;
    float mu = stats[base + t] * inv;
    float var = fmaxf(stats[base + 64 + t] * inv - mu * mu, 0.0f);
    float rs = rsqrtf(var + 1e-5f);
    float s = g[t] * rs;
    sc[t] = s; sh[t] = bt[t] - mu * s;
  }
}

__device__ __forceinline__ void load_y_bn(float (*Xs)[69], const float* __restrict__ y,
    size_t row0, const float* sc, const float* sh, int t) {
  for (int g = t; g < 2048; g += 256) {
    const int r = g >> 4, ch = g & 15;
    float4 v = *(const float4*)(y + (row0 + r) * 64 + ch * 4);
    const int c = ch * 4;
    Xs[r][c+0] = fmaxf(fmaf(sc[c+0], v.x, sh[c+0]), 0.0f);
    Xs[r][c+1] = fmaxf(fmaf(sc[c+1], v.y, sh[c+1]), 0.0f);
    Xs[r][c+2] = fmaxf(fmaf(sc[c+2], v.z, sh[c+2]), 0.0f);
    Xs[r][c+3] = fmaxf(fmaf(sc[c+3], v.w, sh[c+3]), 0.0f);
  }
}

__device__ __forceinline__ void bn_to_Xs(float (*Xs)[69], float acc[8][4],
    const float* sc, const float* sh, int tr, int tc) {
  #pragma unroll
  for (int j = 0; j < 4; ++j) {
    int c = tc*4 + j;
    #pragma unroll
    for (int i = 0; i < 8; ++i)
      Xs[tr*8 + i][c] = fmaxf(fmaf(sc[c], acc[i][j], sh[c]), 0.0f);
  }
}

__device__ __forceinline__ void store_y(float* __restrict__ y, size_t row0,
                                        float acc[8][4], int tr, int tc) {
  #pragma unroll
  for (int i = 0; i < 8; ++i) {
    size_t gr = row0 + tr*8 + i;
    *(float4*)(y + gr * 64 + tc*4) = make_float4(acc[i][0], acc[i][1], acc[i][2], acc[i][3]);
  }
}

__device__ __forceinline__ void stats_acc64(float acc[8][4], float* ssum, float* ssq,
    float* __restrict__ gsum, float* __restrict__ gsq, int tc, int t) {
  #pragma unroll
  for (int j = 0; j < 4; ++j) {
    float s0 = 0.f, s1 = 0.f;
    #pragma unroll
    for (int i = 0; i < 8; ++i) { s0 += acc[i][j]; s1 += acc[i][j]*acc[i][j]; }
    atomicAdd(&ssum[tc*4 + j], s0);
    atomicAdd(&ssq [tc*4 + j], s1);
  }
  __syncthreads();
  if (t < 64) { atomicAdd(&gsum[t], ssum[t]); atomicAdd(&gsq[t], ssq[t]); }
}

// ---------------- pass0: gather + GEMM0 + stats0 (optional y0 store) ----------------
template<bool STORE>
__global__ __launch_bounds__(256) void k_pass0(const float* __restrict__ xyz,
    const float* __restrict__ points, const float* __restrict__ nxyz,
    const ushort_t* __restrict__ ballidx, const float* __restrict__ W0,
    const float* __restrict__ b0, float* __restrict__ y0, float* __restrict__ stats) {
  __shared__ float Xs[128][69];
  __shared__ float Ws[64*69];
  __shared__ float ssum[64], ssq[64];
  const int t = threadIdx.x;
  const int bp4 = blockIdx.x * 4, b = bp4 >> 10;
  const size_t row0 = (size_t)blockIdx.x * 128;
  if (t < 64) { ssum[t] = 0.f; ssq[t] = 0.f; }
  load_W<64,67,69>(Ws, W0, t);
  gather_X(Xs, xyz, points, nxyz, ballidx, bp4, b, t);
  __syncthreads();
  const int tr = t >> 4, tc = t & 15;
  float acc[8][4];
  gemm4<67,69>(Xs, Ws, b0, 0, tr, tc, acc);
  if (STORE) store_y(y0, row0, acc, tr, tc);
  stats_acc64(acc, ssum, ssq, stats, stats + 64, tc, t);
}

// ---------------- pass1: (y0 or recompute) -> BN0 -> GEMM1 + stats1 ----------------
template<bool LOADY0, bool STORE>
__global__ __launch_bounds__(256) void k_pass1(const float* __restrict__ xyz,
    const float* __restrict__ points, const float* __restrict__ nxyz,
    const ushort_t* __restrict__ ballidx,
    const float* __restrict__ W0, const float* __restrict__ b0,
    const float* __restrict__ g0, const float* __restrict__ bt0,
    const float* __restrict__ W1, const float* __restrict__ b1,
    const float* __restrict__ y0, float* __restrict__ y1, float* __restrict__ stats) {
  __shared__ float Xs[128][69];
  __shared__ float Ws[64*69];
  __shared__ float sc[64], sh[64], ssum[64], ssq[64];
  const int t = threadIdx.x;
  const int bp4 = blockIdx.x * 4, b = bp4 >> 10;
  const size_t row0 = (size_t)blockIdx.x * 128;
  if (t < 64) { ssum[t] = 0.f; ssq[t] = 0.f; }
  bn_coef(stats, 0, g0, bt0, sc, sh, t);
  const int tr = t >> 4, tc = t & 15;
  if (LOADY0) {
    load_W<64,64,69>(Ws, W1, t);
    __syncthreads();
    load_y_bn(Xs, y0, row0, sc, sh, t);
    __syncthreads();
  } else {
    load_W<64,67,69>(Ws, W0, t);
    gather_X(Xs, xyz, points, nxyz, ballidx, bp4, b, t);
    __syncthreads();
    float a0[8][4];
    gemm4<67,69>(Xs, Ws, b0, 0, tr, tc, a0);
    __syncthreads();
    bn_to_Xs(Xs, a0, sc, sh, tr, tc);
    load_W<64,64,69>(Ws, W1, t);
    __syncthreads();
  }
  float acc[8][4];
  gemm4<64,69>(Xs, Ws, b1, 0, tr, tc, acc);
  if (STORE) store_y(y1, row0, acc, tr, tc);
  stats_acc64(acc, ssum, ssq, stats + 128, stats + 192, tc, t);
}

// ---- pass2: (y1 / y0 / recompute) -> GEMM2 (two 64-ch halves) + stats2 + pre-BN pool ----
// Pool extremum (max if g2[o]>=0 else min) stored f32 IN PLACE into out's new_points region.
template<int MODE>   // 0 = load y1, 1 = load y0, 2 = recompute all
__global__ __launch_bounds__(256) void k_pass2(const float* __restrict__ xyz,
    const float* __restrict__ points, const float* __restrict__ nxyz,
    const ushort_t* __restrict__ ballidx,
    const float* __restrict__ W0, const float* __restrict__ b0,
    const float* __restrict__ g0, const float* __restrict__ bt0,
    const float* __restrict__ W1, const float* __restrict__ b1,
    const float* __restrict__ g1, const float* __restrict__ bt1,
    const float* __restrict__ W2, const float* __restrict__ b2,
    const float* __restrict__ g2,
    const float* __restrict__ y0, const float* __restrict__ y1,
    float* __restrict__ out, float* __restrict__ stats) {
  __shared__ float Xs[128][69];
  __shared__ float Ws[64*69];      // W0/W1 stages (LDW 69) and W2 halves (LDW 65)
  __shared__ float plex[16*64];
  __shared__ float sc0[64], sh0[64], sc1[64], sh1[64];
  __shared__ float ssum[128], ssq[128], sg[128];
  const int t = threadIdx.x;
  const int bp4 = blockIdx.x * 4, b = bp4 >> 10;
  const size_t row0 = (size_t)blockIdx.x * 128;
  if (t < 128) { ssum[t] = 0.f; ssq[t] = 0.f; sg[t] = g2[t]; }
  bn_coef(stats, 128, g1, bt1, sc1, sh1, t);
  const int tr = t >> 4, tc = t & 15;
  if (MODE == 0) {
    load_y_bn(Xs, y1, row0, sc1, sh1, t);
  } else {
    bn_coef(stats, 0, g0, bt0, sc0, sh0, t);
    if (MODE == 1) {
      load_W<64,64,69>(Ws, W1, t);
      __syncthreads();
      load_y_bn(Xs, y0, row0, sc0, sh0, t);
      __syncthreads();
    } else {
      load_W<64,67,69>(Ws, W0, t);
      gather_X(Xs, xyz, points, nxyz, ballidx, bp4, b, t);
      __syncthreads();
      float a0[8][4];
      gemm4<67,69>(Xs, Ws, b0, 0, tr, tc, a0);
      __syncthreads();
      bn_to_Xs(Xs, a0, sc0, sh0, tr, tc);
      load_W<64,64,69>(Ws, W1, t);
      __syncthreads();
    }
    float a1[8][4];
    gemm4<64,69>(Xs, Ws, b1, 0, tr, tc, a1);
    __syncthreads();
    bn_to_Xs(Xs, a1, sc1, sh1, tr, tc);
  }
  // two 64-channel halves of the N=128 GEMM
  for (int h = 0; h < 2; ++h) {
    load_W<64,64,65>(Ws, W2 + h * 64 * 64, t);
    __syncthreads();                       // Ws + Xs ready (also covers pre-loop Xs writes)
    float acc[8][4];
    gemm4<64,65>(Xs, Ws, b2, h * 64, tr, tc, acc);
    #pragma unroll
    for (int j = 0; j < 4; ++j) {
      float s0 = 0.f, s1 = 0.f;
      #pragma unroll
      for (int i = 0; i < 8; ++i) { s0 += acc[i][j]; s1 += acc[i][j]*acc[i][j]; }
      atomicAdd(&ssum[h*64 + tc*4 + j], s0);
      atomicAdd(&ssq [h*64 + tc*4 + j], s1);
    }
    #pragma unroll
    for (int j = 0; j < 4; ++j) {
      const bool useMax = sg[h*64 + tc*4 + j] >= 0.0f;
      float e = acc[0][j];
      #pragma unroll
      for (int i = 1; i < 8; ++i) e = useMax ? fmaxf(e, acc[i][j]) : fminf(e, acc[i][j]);
      plex[tr * 64 + tc*4 + j] = e;
    }
    __syncthreads();                       // plex complete (all gemms of this half done)
    {
      const int pl = t >> 6, o = t & 63;   // 4 pairs x 64 channels
      const bool useMax = sg[h*64 + o] >= 0.0f;
      float e = plex[(pl*4 + 0) * 64 + o];
      #pragma unroll
      for (int i = 1; i < 4; ++i) {
        float v = plex[(pl*4 + i) * 64 + o];
        e = useMax ? fmaxf(e, v) : fminf(e, v);
      }
      out[OUT_NP_OFF + (size_t)(bp4 + pl) * 128 + h*64 + o] = e;
    }
    // next-half load_W is gated by the top-of-loop __syncthreads
  }
  __syncthreads();
  if (t < 128) { atomicAdd(&stats[256 + t], ssum[t]); atomicAdd(&stats[384 + t], ssq[t]); }
}

// ---------------- final: BN2+ReLU applied in place to pooled extrema ----------------
__global__ __launch_bounds__(256) void k_final(const float* __restrict__ stats,
                                               const float* __restrict__ g2,
                                               const float* __restrict__ bt2,
                                               float* __restrict__ out) {
  const int gid = blockIdx.x * 256 + threadIdx.x;   // < 2097152
  const int o = gid & 127;
  const float inv = 1.0f / CNT_TOTAL;
  float mu = stats[256 + o] * inv;
  float var = fmaxf(stats[384 + o] * inv - mu * mu, 0.0f);
  float rs = rsqrtf(var + 1e-5f);
  float s = g2[o] * rs;
  float b = bt2[o] - mu * s;
  float v = out[OUT_NP_OFF + gid];
  out[OUT_NP_OFF + gid] = fmaxf(fmaf(s, v, b), 0.0f);   // monotone BN+ReLU commutes with pool
}

extern "C" void kernel_launch(void* const* d_in, const int* in_sizes, int n_in,
                              void* d_out, int out_size, void* d_ws, size_t ws_size,
                              hipStream_t stream) {
  (void)in_sizes; (void)n_in; (void)out_size;
  const float* xyz    = (const float*)d_in[0];
  const float* points = (const float*)d_in[1];
  const float* W0  = (const float*)d_in[2];
  const float* b0  = (const float*)d_in[3];
  const float* g0  = (const float*)d_in[4];
  const float* bt0 = (const float*)d_in[5];
  const float* W1  = (const float*)d_in[6];
  const float* b1  = (const float*)d_in[7];
  const float* g1  = (const float*)d_in[8];
  const float* bt1 = (const float*)d_in[9];
  const float* W2  = (const float*)d_in[10];
  const float* b2  = (const float*)d_in[11];
  const float* g2  = (const float*)d_in[12];
  const float* bt2 = (const float*)d_in[13];
  float* out = (float*)d_out;

  // Workspace: stats 2 KB + ballidx 1 MB mandatory; y0/y1 (f32, 134 MB each) only if room.
  const size_t statsB = 2048;
  const size_t ballB  = (size_t)16384 * NK * 2;       // 1,048,576
  const size_t MINWS  = statsB + ballB;               // 1,050,624
  const size_t yB     = (size_t)524288 * 64 * 4;      // 134,217,728

  char* ws = (char*)d_ws;
  float* stats      = (float*)ws;
  ushort_t* ballidx = (ushort_t*)(ws + statsB);
  float* y0         = (float*)(ws + MINWS);
  float* y1         = (float*)(ws + MINWS + yB);

  hipMemsetAsync(stats, 0, statsB, stream);
  k_fps <<<dim3(NB),   dim3(1024), 0, stream>>>(xyz, out);
  k_ball<<<dim3(4096), dim3(256),  0, stream>>>(xyz, out, ballidx);

  if (ws_size >= MINWS + 2 * yB) {
    k_pass0<true>        <<<dim3(4096), dim3(256), 0, stream>>>(xyz, points, out, ballidx, W0, b0, y0, stats);
    k_pass1<true, true>  <<<dim3(4096), dim3(256), 0, stream>>>(xyz, points, out, ballidx, W0, b0, g0, bt0, W1, b1, y0, y1, stats);
    k_pass2<0>           <<<dim3(4096), dim3(256), 0, stream>>>(xyz, points, out, ballidx, W0, b0, g0, bt0, W1, b1, g1, bt1, W2, b2, g2, y0, y1, out, stats);
  } else if (ws_size >= MINWS + yB) {
    k_pass0<true>        <<<dim3(4096), dim3(256), 0, stream>>>(xyz, points, out, ballidx, W0, b0, y0, stats);
    k_pass1<true, false> <<<dim3(4096), dim3(256), 0, stream>>>(xyz, points, out, ballidx, W0, b0, g0, bt0, W1, b1, y0, y1, stats);
    k_pass2<1>           <<<dim3(4096), dim3(256), 0, stream>>>(xyz, points, out, ballidx, W0, b0, g0, bt0, W1, b1, g1, bt1, W2, b2, g2, y0, y1, out, stats);
  } else {
    k_pass0<false>       <<<dim3(4096), dim3(256), 0, stream>>>(xyz, points, out, ballidx, W0, b0, y0, stats);
    k_pass1<false, false><<<dim3(4096), dim3(256), 0, stream>>>(xyz, points, out, ballidx, W0, b0, g0, bt0, W1, b1, y0, y1, stats);
    k_pass2<2>           <<<dim3(4096), dim3(256), 0, stream>>>(xyz, points, out, ballidx, W0, b0, g0, bt0, W1, b1, g1, bt1, W2, b2, g2, y0, y1, out, stats);
  }
  k_final<<<dim3(8192), dim3(256), 0, stream>>>(stats, g2, bt2, out);
}

// Round 6
// 1724.959 us; speedup vs baseline: 1.3802x; 1.3802x over previous
//
#include <hip/hip_runtime.h>

typedef unsigned int u32;
typedef unsigned long long u64;
typedef unsigned short ushort_t;

#define NB 16
#define NPT 4096
#define NS 1024
#define NK 32
#define ND 64
#define CNT_TOTAL 524288.0f   // 16*1024*32
#define OUT_NP_OFF 49152      // new_points offset in d_out (f32 elements)

// ---------------- FPS: one block per batch, points in registers ----------------
// 512 threads, 8 points/thread in VGPRs; LDS copy only for centroid lookup.
// One barrier/iteration via double-buffered warr.
__global__ __launch_bounds__(512) void k_fps(const float* __restrict__ xyz,
                                             float* __restrict__ out_xyz) {
  __shared__ float sx[NPT], sy[NPT], sz[NPT];
  __shared__ u64 warr[2][8];
  const int b = blockIdx.x, t = threadIdx.x;
  const float* xb = xyz + (size_t)b * NPT * 3;
  float px[8], py[8], pz[8], dst[8];
  #pragma unroll
  for (int k = 0; k < 8; ++k) {
    const int n = t + 512 * k;
    const float x = xb[3*n+0], y = xb[3*n+1], z = xb[3*n+2];
    px[k] = x; py[k] = y; pz[k] = z;
    sx[n] = x; sy[n] = y; sz[n] = z;
    dst[k] = 1e10f;
  }
  __syncthreads();
  int f = 0;
  float* ob = out_xyz + (size_t)b * NS * 3;
  const int lane = t & 63, w = t >> 6;
  for (int it = 0; it < NS; ++it) {
    if (t == 0) { ob[3*it+0] = sx[f]; ob[3*it+1] = sy[f]; ob[3*it+2] = sz[f]; }
    const float cx = sx[f], cy = sy[f], cz = sz[f];
    float d[8];
    // exact numpy order: ((dx*dx + dy*dy) + dz*dz), then minimum-update
    #pragma unroll
    for (int k = 0; k < 8; ++k) {
      float dx = __fsub_rn(px[k], cx), dy = __fsub_rn(py[k], cy), dz = __fsub_rn(pz[k], cz);
      float dd = __fadd_rn(__fadd_rn(__fmul_rn(dx,dx), __fmul_rn(dy,dy)), __fmul_rn(dz,dz));
      dd = fminf(dst[k], dd);
      dst[k] = dd; d[k] = dd;
    }
    float bv = d[0];
    #pragma unroll
    for (int k = 1; k < 8; ++k) bv = fmaxf(bv, d[k]);
    int bi = 0;
    #pragma unroll
    for (int k = 7; k >= 0; --k) if (d[k] == bv) bi = t + 512 * k;   // first-max (lowest k)
    // key: (value desc, index asc); d >= 0 so float bits are monotone
    u64 best = ((u64)__float_as_uint(bv) << 32) | (u32)(NPT - 1 - bi);
    #pragma unroll
    for (int sft = 32; sft >= 1; sft >>= 1) {
      u64 o = __shfl_xor(best, sft, 64);
      if (o > best) best = o;
    }
    if (lane == 0) warr[it & 1][w] = best;
    __syncthreads();
    u64 m = warr[it & 1][0];
    #pragma unroll
    for (int i = 1; i < 8; ++i) { u64 o = warr[it & 1][i]; if (o > m) m = o; }
    f = NPT - 1 - (int)(m & 0xffffffffu);   // always in [0, 4095]
  }
}

// ---------------- Ball query: one wave per (b,s) pair ----------------
#define SQCAP 1024
__global__ __launch_bounds__(256) void k_ball(const float* __restrict__ xyz,
                                              const float* __restrict__ nxyz,
                                              ushort_t* __restrict__ ballidx) {
  __shared__ u64 keys[4][SQCAP];
  const int w = threadIdx.x >> 6, lane = threadIdx.x & 63;
  const int pair = blockIdx.x * 4 + w;
  const int b = pair >> 10;
  const float* xb = xyz + (size_t)b * NPT * 3;
  const float nx = nxyz[(size_t)pair*3+0];
  const float ny = nxyz[(size_t)pair*3+1];
  const float nz = nxyz[(size_t)pair*3+2];
  const float ssn = __fadd_rn(__fadd_rn(__fmul_rn(nx,nx), __fmul_rn(ny,ny)), __fmul_rn(nz,nz));
  int cnt = 0;
  for (int n0 = 0; n0 < NPT; n0 += 64) {
    const int n = n0 + lane;
    const float px = xb[3*n+0], py = xb[3*n+1], pz = xb[3*n+2];
    const float ssx = __fadd_rn(__fadd_rn(__fmul_rn(px,px), __fmul_rn(py,py)), __fmul_rn(pz,pz));
    const float dt  = __fadd_rn(__fadd_rn(__fmul_rn(nx,px), __fmul_rn(ny,py)), __fmul_rn(nz,pz));
    const float d   = __fsub_rn(__fadd_rn(ssn, ssx), __fmul_rn(2.0f, dt));
    const bool in = !(d > 0.04f);   // keep d <= radius^2
    const u64 mask = __ballot(in);
    if (in) {
      int pos = cnt + (int)__popcll(mask & ((1ull << lane) - 1ull));
      if (pos < SQCAP) {
        u32 bits = __float_as_uint(d);
        u32 mapped = (bits & 0x80000000u) ? ~bits : (bits | 0x80000000u); // total order incl. negatives
        keys[w][pos] = ((u64)mapped << 32) | (u32)n;
      }
    }
    cnt += (int)__popcll(mask);
  }
  if (cnt > SQCAP) cnt = SQCAP;
  ushort_t* op = ballidx + (size_t)pair * NK;
  int first = 0;
  volatile u64* kp = &keys[w][0];
  for (int iter = 0; iter < NK; ++iter) {
    if (iter < cnt) {
      u64 mb = ~0ull;
      for (int i = lane; i < cnt; i += 64) { u64 kk = kp[i]; if (kk < mb) mb = kk; }
      #pragma unroll
      for (int sft = 32; sft >= 1; sft >>= 1) {
        u64 o = __shfl_xor(mb, sft, 64);
        if (o < mb) mb = o;
      }
      for (int i = lane; i < cnt; i += 64) { if (kp[i] == mb) kp[i] = ~0ull; }
      const int widx = (int)(mb & 0xffffffffu);
      if (iter == 0) first = widx;
      if (lane == 0) op[iter] = (ushort_t)widx;
    } else {
      if (lane == 0) op[iter] = (ushort_t)first;
    }
  }
}

// ================= shared helpers for conv passes (all f32) =================
template<int ROWS, int K, int LDW>
__device__ __forceinline__ void load_W(float* Ws, const float* __restrict__ W, int t) {
  for (int e = t; e < ROWS * K; e += 256) Ws[(e / K) * LDW + (e % K)] = W[e];
}

__device__ __forceinline__ void gather_X(float (*Xs)[69],
    const float* __restrict__ xyz, const float* __restrict__ points,
    const float* __restrict__ nxyz, const ushort_t* __restrict__ ballidx,
    int bp4, int b, int t) {
  if (t < 128) {
    const int pair = bp4 + (t >> 5);
    const int idx = (int)ballidx[pair * NK + (t & 31)];
    const float* p = xyz + ((size_t)b * NPT + idx) * 3;
    const float* nzp = nxyz + (size_t)pair * 3;
    Xs[t][0] = __fsub_rn(p[0], nzp[0]);
    Xs[t][1] = __fsub_rn(p[1], nzp[1]);
    Xs[t][2] = __fsub_rn(p[2], nzp[2]);
  }
  for (int g = t; g < 2048; g += 256) {
    const int r = g >> 4, ch = g & 15;
    const int pair = bp4 + (r >> 5);
    const int idx = (int)ballidx[pair * NK + (r & 31)];
    float4 v = *(const float4*)(points + ((size_t)b * NPT + idx) * ND + ch * 4);
    Xs[r][3 + ch*4 + 0] = v.x; Xs[r][3 + ch*4 + 1] = v.y;
    Xs[r][3 + ch*4 + 2] = v.z; Xs[r][3 + ch*4 + 3] = v.w;
  }
}

template<int K, int LDW>
__device__ __forceinline__ void gemm4(const float (*Xs)[69], const float* Ws,
                                      const float* __restrict__ bias, int biasOff,
                                      int tr, int tc, float acc[8][4]) {
  #pragma unroll
  for (int j = 0; j < 4; ++j) {
    float bb = bias[biasOff + tc*4 + j];
    #pragma unroll
    for (int i = 0; i < 8; ++i) acc[i][j] = bb;
  }
  for (int c = 0; c < K; ++c) {
    float wv[4];
    #pragma unroll
    for (int j = 0; j < 4; ++j) wv[j] = Ws[(tc*4 + j) * LDW + c];
    #pragma unroll
    for (int i = 0; i < 8; ++i) {
      float xv = Xs[tr*8 + i][c];
      #pragma unroll
      for (int j = 0; j < 4; ++j) acc[i][j] = fmaf(xv, wv[j], acc[i][j]);
    }
  }
}

__device__ __forceinline__ void bn_coef(const float* __restrict__ stats, int base,
    const float* __restrict__ g, const float* __restrict__ bt,
    float* sc, float* sh, int t) {
  if (t < 64) {
    const float inv = 1.0f / CNT_TOTAL;
    float mu = stats[base + t] * inv;
    float var = fmaxf(stats[base + 64 + t] * inv - mu * mu, 0.0f);
    float rs = rsqrtf(var + 1e-5f);
    float s = g[t] * rs;
    sc[t] = s; sh[t] = bt[t] - mu * s;
  }
}

__device__ __forceinline__ void load_y_bn(float (*Xs)[69], const float* __restrict__ y,
    size_t row0, const float* sc, const float* sh, int t) {
  for (int g = t; g < 2048; g += 256) {
    const int r = g >> 4, ch = g & 15;
    float4 v = *(const float4*)(y + (row0 + r) * 64 + ch * 4);
    const int c = ch * 4;
    Xs[r][c+0] = fmaxf(fmaf(sc[c+0], v.x, sh[c+0]), 0.0f);
    Xs[r][c+1] = fmaxf(fmaf(sc[c+1], v.y, sh[c+1]), 0.0f);
    Xs[r][c+2] = fmaxf(fmaf(sc[c+2], v.z, sh[c+2]), 0.0f);
    Xs[r][c+3] = fmaxf(fmaf(sc[c+3], v.w, sh[c+3]), 0.0f);
  }
}

__device__ __forceinline__ void bn_to_Xs(float (*Xs)[69], float acc[8][4],
    const float* sc, const float* sh, int tr, int tc) {
  #pragma unroll
  for (int j = 0; j < 4; ++j) {
    int c = tc*4 + j;
    #pragma unroll
    for (int i = 0; i < 8; ++i)
      Xs[tr*8 + i][c] = fmaxf(fmaf(sc[c], acc[i][j], sh[c]), 0.0f);
  }
}

__device__ __forceinline__ void store_y(float* __restrict__ y, size_t row0,
                                        float acc[8][4], int tr, int tc) {
  #pragma unroll
  for (int i = 0; i < 8; ++i) {
    size_t gr = row0 + tr*8 + i;
    *(float4*)(y + gr * 64 + tc*4) = make_float4(acc[i][0], acc[i][1], acc[i][2], acc[i][3]);
  }
}

__device__ __forceinline__ void stats_acc64(float acc[8][4], float* ssum, float* ssq,
    float* __restrict__ gsum, float* __restrict__ gsq, int tc, int t) {
  #pragma unroll
  for (int j = 0; j < 4; ++j) {
    float s0 = 0.f, s1 = 0.f;
    #pragma unroll
    for (int i = 0; i < 8; ++i) { s0 += acc[i][j]; s1 += acc[i][j]*acc[i][j]; }
    atomicAdd(&ssum[tc*4 + j], s0);
    atomicAdd(&ssq [tc*4 + j], s1);
  }
  __syncthreads();
  if (t < 64) { atomicAdd(&gsum[t], ssum[t]); atomicAdd(&gsq[t], ssq[t]); }
}

// ---------------- pass0: gather + GEMM0 + stats0 (optional y0 store) ----------------
template<bool STORE>
__global__ __launch_bounds__(256) void k_pass0(const float* __restrict__ xyz,
    const float* __restrict__ points, const float* __restrict__ nxyz,
    const ushort_t* __restrict__ ballidx, const float* __restrict__ W0,
    const float* __restrict__ b0, float* __restrict__ y0, float* __restrict__ stats) {
  __shared__ float Xs[128][69];
  __shared__ float Ws[64*69];
  __shared__ float ssum[64], ssq[64];
  const int t = threadIdx.x;
  const int bp4 = blockIdx.x * 4, b = bp4 >> 10;
  const size_t row0 = (size_t)blockIdx.x * 128;
  if (t < 64) { ssum[t] = 0.f; ssq[t] = 0.f; }
  load_W<64,67,69>(Ws, W0, t);
  gather_X(Xs, xyz, points, nxyz, ballidx, bp4, b, t);
  __syncthreads();
  const int tr = t >> 4, tc = t & 15;
  float acc[8][4];
  gemm4<67,69>(Xs, Ws, b0, 0, tr, tc, acc);
  if (STORE) store_y(y0, row0, acc, tr, tc);
  stats_acc64(acc, ssum, ssq, stats, stats + 64, tc, t);
}

// ---------------- pass1: (y0 or recompute) -> BN0 -> GEMM1 + stats1 ----------------
template<bool LOADY0, bool STORE>
__global__ __launch_bounds__(256) void k_pass1(const float* __restrict__ xyz,
    const float* __restrict__ points, const float* __restrict__ nxyz,
    const ushort_t* __restrict__ ballidx,
    const float* __restrict__ W0, const float* __restrict__ b0,
    const float* __restrict__ g0, const float* __restrict__ bt0,
    const float* __restrict__ W1, const float* __restrict__ b1,
    const float* __restrict__ y0, float* __restrict__ y1, float* __restrict__ stats) {
  __shared__ float Xs[128][69];
  __shared__ float Ws[64*69];
  __shared__ float sc[64], sh[64], ssum[64], ssq[64];
  const int t = threadIdx.x;
  const int bp4 = blockIdx.x * 4, b = bp4 >> 10;
  const size_t row0 = (size_t)blockIdx.x * 128;
  if (t < 64) { ssum[t] = 0.f; ssq[t] = 0.f; }
  bn_coef(stats, 0, g0, bt0, sc, sh, t);
  const int tr = t >> 4, tc = t & 15;
  if (LOADY0) {
    load_W<64,64,69>(Ws, W1, t);
    __syncthreads();
    load_y_bn(Xs, y0, row0, sc, sh, t);
    __syncthreads();
  } else {
    load_W<64,67,69>(Ws, W0, t);
    gather_X(Xs, xyz, points, nxyz, ballidx, bp4, b, t);
    __syncthreads();
    float a0[8][4];
    gemm4<67,69>(Xs, Ws, b0, 0, tr, tc, a0);
    __syncthreads();
    bn_to_Xs(Xs, a0, sc, sh, tr, tc);
    load_W<64,64,69>(Ws, W1, t);
    __syncthreads();
  }
  float acc[8][4];
  gemm4<64,69>(Xs, Ws, b1, 0, tr, tc, acc);
  if (STORE) store_y(y1, row0, acc, tr, tc);
  stats_acc64(acc, ssum, ssq, stats + 128, stats + 192, tc, t);
}

// ---- pass2: (y1 / y0 / recompute) -> GEMM2 (two 64-ch halves) + stats2 + pre-BN pool ----
// Pool extremum (max if g2[o]>=0 else min) stored f32 IN PLACE into out's new_points region.
template<int MODE>   // 0 = load y1, 1 = load y0, 2 = recompute all
__global__ __launch_bounds__(256) void k_pass2(const float* __restrict__ xyz,
    const float* __restrict__ points, const float* __restrict__ nxyz,
    const ushort_t* __restrict__ ballidx,
    const float* __restrict__ W0, const float* __restrict__ b0,
    const float* __restrict__ g0, const float* __restrict__ bt0,
    const float* __restrict__ W1, const float* __restrict__ b1,
    const float* __restrict__ g1, const float* __restrict__ bt1,
    const float* __restrict__ W2, const float* __restrict__ b2,
    const float* __restrict__ g2,
    const float* __restrict__ y0, const float* __restrict__ y1,
    float* __restrict__ out, float* __restrict__ stats) {
  __shared__ float Xs[128][69];
  __shared__ float Ws[64*69];      // W0/W1 stages (LDW 69) and W2 halves (LDW 65)
  __shared__ float plex[16*64];
  __shared__ float sc0[64], sh0[64], sc1[64], sh1[64];
  __shared__ float ssum[128], ssq[128], sg[128];
  const int t = threadIdx.x;
  const int bp4 = blockIdx.x * 4, b = bp4 >> 10;
  const size_t row0 = (size_t)blockIdx.x * 128;
  if (t < 128) { ssum[t] = 0.f; ssq[t] = 0.f; sg[t] = g2[t]; }
  bn_coef(stats, 128, g1, bt1, sc1, sh1, t);
  const int tr = t >> 4, tc = t & 15;
  if (MODE == 0) {
    load_y_bn(Xs, y1, row0, sc1, sh1, t);
  } else {
    bn_coef(stats, 0, g0, bt0, sc0, sh0, t);
    if (MODE == 1) {
      load_W<64,64,69>(Ws, W1, t);
      __syncthreads();
      load_y_bn(Xs, y0, row0, sc0, sh0, t);
      __syncthreads();
    } else {
      load_W<64,67,69>(Ws, W0, t);
      gather_X(Xs, xyz, points, nxyz, ballidx, bp4, b, t);
      __syncthreads();
      float a0[8][4];
      gemm4<67,69>(Xs, Ws, b0, 0, tr, tc, a0);
      __syncthreads();
      bn_to_Xs(Xs, a0, sc0, sh0, tr, tc);
      load_W<64,64,69>(Ws, W1, t);
      __syncthreads();
    }
    float a1[8][4];
    gemm4<64,69>(Xs, Ws, b1, 0, tr, tc, a1);
    __syncthreads();
    bn_to_Xs(Xs, a1, sc1, sh1, tr, tc);
  }
  // two 64-channel halves of the N=128 GEMM
  for (int h = 0; h < 2; ++h) {
    load_W<64,64,65>(Ws, W2 + h * 64 * 64, t);
    __syncthreads();                       // Ws + Xs ready (also covers pre-loop Xs writes)
    float acc[8][4];
    gemm4<64,65>(Xs, Ws, b2, h * 64, tr, tc, acc);
    #pragma unroll
    for (int j = 0; j < 4; ++j) {
      float s0 = 0.f, s1 = 0.f;
      #pragma unroll
      for (int i = 0; i < 8; ++i) { s0 += acc[i][j]; s1 += acc[i][j]*acc[i][j]; }
      atomicAdd(&ssum[h*64 + tc*4 + j], s0);
      atomicAdd(&ssq [h*64 + tc*4 + j], s1);
    }
    #pragma unroll
    for (int j = 0; j < 4; ++j) {
      const bool useMax = sg[h*64 + tc*4 + j] >= 0.0f;
      float e = acc[0][j];
      #pragma unroll
      for (int i = 1; i < 8; ++i) e = useMax ? fmaxf(e, acc[i][j]) : fminf(e, acc[i][j]);
      plex[tr * 64 + tc*4 + j] = e;
    }
    __syncthreads();                       // plex complete (all gemms of this half done)
    {
      const int pl = t >> 6, o = t & 63;   // 4 pairs x 64 channels
      const bool useMax = sg[h*64 + o] >= 0.0f;
      float e = plex[(pl*4 + 0) * 64 + o];
      #pragma unroll
      for (int i = 1; i < 4; ++i) {
        float v = plex[(pl*4 + i) * 64 + o];
        e = useMax ? fmaxf(e, v) : fminf(e, v);
      }
      out[OUT_NP_OFF + (size_t)(bp4 + pl) * 128 + h*64 + o] = e;
    }
    // next-half load_W is gated by the top-of-loop __syncthreads
  }
  __syncthreads();
  if (t < 128) { atomicAdd(&stats[256 + t], ssum[t]); atomicAdd(&stats[384 + t], ssq[t]); }
}

// ---------------- final: BN2+ReLU applied in place to pooled extrema ----------------
__global__ __launch_bounds__(256) void k_final(const float* __restrict__ stats,
                                               const float* __restrict__ g2,
                                               const float* __restrict__ bt2,
                                               float* __restrict__ out) {
  const int gid = blockIdx.x * 256 + threadIdx.x;   // < 2097152
  const int o = gid & 127;
  const float inv = 1.0f / CNT_TOTAL;
  float mu = stats[256 + o] * inv;
  float var = fmaxf(stats[384 + o] * inv - mu * mu, 0.0f);
  float rs = rsqrtf(var + 1e-5f);
  float s = g2[o] * rs;
  float b = bt2[o] - mu * s;
  float v = out[OUT_NP_OFF + gid];
  out[OUT_NP_OFF + gid] = fmaxf(fmaf(s, v, b), 0.0f);   // monotone BN+ReLU commutes with pool
}

extern "C" void kernel_launch(void* const* d_in, const int* in_sizes, int n_in,
                              void* d_out, int out_size, void* d_ws, size_t ws_size,
                              hipStream_t stream) {
  (void)in_sizes; (void)n_in; (void)out_size;
  const float* xyz    = (const float*)d_in[0];
  const float* points = (const float*)d_in[1];
  const float* W0  = (const float*)d_in[2];
  const float* b0  = (const float*)d_in[3];
  const float* g0  = (const float*)d_in[4];
  const float* bt0 = (const float*)d_in[5];
  const float* W1  = (const float*)d_in[6];
  const float* b1  = (const float*)d_in[7];
  const float* g1  = (const float*)d_in[8];
  const float* bt1 = (const float*)d_in[9];
  const float* W2  = (const float*)d_in[10];
  const float* b2  = (const float*)d_in[11];
  const float* g2  = (const float*)d_in[12];
  const float* bt2 = (const float*)d_in[13];
  float* out = (float*)d_out;

  // Workspace: stats 2 KB + ballidx 1 MB mandatory; y0/y1 (f32, 134 MB each) only if room.
  const size_t statsB = 2048;
  const size_t ballB  = (size_t)16384 * NK * 2;       // 1,048,576
  const size_t MINWS  = statsB + ballB;               // 1,050,624
  const size_t yB     = (size_t)524288 * 64 * 4;      // 134,217,728

  char* ws = (char*)d_ws;
  float* stats      = (float*)ws;
  ushort_t* ballidx = (ushort_t*)(ws + statsB);
  float* y0         = (float*)(ws + MINWS);
  float* y1         = (float*)(ws + MINWS + yB);

  hipMemsetAsync(stats, 0, statsB, stream);
  k_fps <<<dim3(NB),   dim3(512),  0, stream>>>(xyz, out);
  k_ball<<<dim3(4096), dim3(256),  0, stream>>>(xyz, out, ballidx);

  if (ws_size >= MINWS + 2 * yB) {
    k_pass0<true>        <<<dim3(4096), dim3(256), 0, stream>>>(xyz, points, out, ballidx, W0, b0, y0, stats);
    k_pass1<true, true>  <<<dim3(4096), dim3(256), 0, stream>>>(xyz, points, out, ballidx, W0, b0, g0, bt0, W1, b1, y0, y1, stats);
    k_pass2<0>           <<<dim3(4096), dim3(256), 0, stream>>>(xyz, points, out, ballidx, W0, b0, g0, bt0, W1, b1, g1, bt1, W2, b2, g2, y0, y1, out, stats);
  } else if (ws_size >= MINWS + yB) {
    k_pass0<true>        <<<dim3(4096), dim3(256), 0, stream>>>(xyz, points, out, ballidx, W0, b0, y0, stats);
    k_pass1<true, false> <<<dim3(4096), dim3(256), 0, stream>>>(xyz, points, out, ballidx, W0, b0, g0, bt0, W1, b1, y0, y1, stats);
    k_pass2<1>           <<<dim3(4096), dim3(256), 0, stream>>>(xyz, points, out, ballidx, W0, b0, g0, bt0, W1, b1, g1, bt1, W2, b2, g2, y0, y1, out, stats);
  } else {
    k_pass0<false>       <<<dim3(4096), dim3(256), 0, stream>>>(xyz, points, out, ballidx, W0, b0, y0, stats);
    k_pass1<false, false><<<dim3(4096), dim3(256), 0, stream>>>(xyz, points, out, ballidx, W0, b0, g0, bt0, W1, b1, y0, y1, stats);
    k_pass2<2>           <<<dim3(4096), dim3(256), 0, stream>>>(xyz, points, out, ballidx, W0, b0, g0, bt0, W1, b1, g1, bt1, W2, b2, g2, y0, y1, out, stats);
  }
  k_final<<<dim3(8192), dim3(256), 0, stream>>>(stats, g2, bt2, out);
}

// Round 7
// 1713.824 us; speedup vs baseline: 1.3891x; 1.0065x over previous
//
#include <hip/hip_runtime.h>

typedef unsigned int u32;
typedef unsigned long long u64;
typedef unsigned short ushort_t;

#define NB 16
#define NPT 4096
#define NS 1024
#define NK 32
#define ND 64
#define CNT_TOTAL 524288.0f   // 16*1024*32
#define OUT_NP_OFF 49152      // new_points offset in d_out (f32 elements)

// DPP helpers (CDNA gfx9-lineage row_shr / row_bcast controls; wave64 = 4 rows of 16).
// update_dpp(old=x, src=x, ..., bound_ctrl=false): invalid source lanes keep x (identity).
#define DPP_FMAX(x, CTRL)                                                     \
  x = fmaxf(x, __int_as_float(__builtin_amdgcn_update_dpp(                    \
      __float_as_int(x), __float_as_int(x), CTRL, 0xf, 0xf, false)))

__device__ __forceinline__ float wave_max_f32_lane63(float x) {
  DPP_FMAX(x, 0x111);  // row_shr:1
  DPP_FMAX(x, 0x112);  // row_shr:2
  DPP_FMAX(x, 0x114);  // row_shr:4
  DPP_FMAX(x, 0x118);  // row_shr:8  -> lane15/31/47/63 hold row maxes
  DPP_FMAX(x, 0x142);  // row_bcast15 -> lane31 = rows0-1, lane63 = rows2-3
  DPP_FMAX(x, 0x143);  // row_bcast31 -> lane63 = full wave max
  return __int_as_float(__builtin_amdgcn_readlane(__float_as_int(x), 63));
}

__device__ __forceinline__ u64 wave_min_u64_bcast(u64 x) {
  #define DPP_MINU64(CTRL) {                                                  \
    int hi = (int)(x >> 32), lo = (int)(u32)x;                                \
    int h2 = __builtin_amdgcn_update_dpp(hi, hi, CTRL, 0xf, 0xf, false);      \
    int l2 = __builtin_amdgcn_update_dpp(lo, lo, CTRL, 0xf, 0xf, false);      \
    u64 y = ((u64)(u32)h2 << 32) | (u32)l2;                                   \
    if (y < x) x = y; }
  DPP_MINU64(0x111) DPP_MINU64(0x112) DPP_MINU64(0x114) DPP_MINU64(0x118)
  DPP_MINU64(0x142) DPP_MINU64(0x143)
  #undef DPP_MINU64
  u32 hi = (u32)__builtin_amdgcn_readlane((int)(x >> 32), 63);
  u32 lo = (u32)__builtin_amdgcn_readlane((int)(u32)x, 63);
  return ((u64)hi << 32) | lo;
}

// ---------------- FPS: one block per batch; DPP reduce; coords travel with key ----------------
// 512 threads; thread t owns contiguous points [8t, 8t+8) so lane order == index order.
__global__ __launch_bounds__(512) void k_fps(const float* __restrict__ xyz,
                                             float* __restrict__ out_xyz) {
  __shared__ u64 wkey[2][8];
  __shared__ float wcrd[2][8][3];
  const int b = blockIdx.x, t = threadIdx.x;
  const int lane = t & 63, w = t >> 6;
  const float* xb = xyz + (size_t)b * NPT * 3;
  float px[8], py[8], pz[8], dst[8];
  {
    const float4* s4 = (const float4*)(xb + t * 24);
    float4 v0 = s4[0], v1 = s4[1], v2 = s4[2], v3 = s4[3], v4 = s4[4], v5 = s4[5];
    px[0]=v0.x; py[0]=v0.y; pz[0]=v0.z;  px[1]=v0.w; py[1]=v1.x; pz[1]=v1.y;
    px[2]=v1.z; py[2]=v1.w; pz[2]=v2.x;  px[3]=v2.y; py[3]=v2.z; pz[3]=v2.w;
    px[4]=v3.x; py[4]=v3.y; pz[4]=v3.z;  px[5]=v3.w; py[5]=v4.x; pz[5]=v4.y;
    px[6]=v4.z; py[6]=v4.w; pz[6]=v5.x;  px[7]=v5.y; py[7]=v5.z; pz[7]=v5.w;
  }
  #pragma unroll
  for (int k = 0; k < 8; ++k) dst[k] = 1e10f;
  float fx = xb[0], fy = xb[1], fz = xb[2];   // farthest = 0 initially
  float* ob = out_xyz + (size_t)b * NS * 3;
  for (int it = 0; it < NS; ++it) {
    if (t == 0) { ob[3*it+0] = fx; ob[3*it+1] = fy; ob[3*it+2] = fz; }
    float d[8];
    // exact numpy order: ((dx*dx + dy*dy) + dz*dz), then minimum-update
    #pragma unroll
    for (int k = 0; k < 8; ++k) {
      float dx = __fsub_rn(px[k], fx), dy = __fsub_rn(py[k], fy), dz = __fsub_rn(pz[k], fz);
      float dd = __fadd_rn(__fadd_rn(__fmul_rn(dx,dx), __fmul_rn(dy,dy)), __fmul_rn(dz,dz));
      dd = fminf(dst[k], dd);
      dst[k] = dd; d[k] = dd;
    }
    float bv = d[0];
    #pragma unroll
    for (int k = 1; k < 8; ++k) bv = fmaxf(bv, d[k]);
    int bk = 7; float bx = px[7], by = py[7], bz = pz[7];
    #pragma unroll
    for (int k = 6; k >= 0; --k) {        // lowest k achieving bv (first-max)
      bool e = (d[k] == bv);
      bk = e ? k : bk; bx = e ? px[k] : bx; by = e ? py[k] : by; bz = e ? pz[k] : bz;
    }
    const float wmax = wave_max_f32_lane63(bv);
    const u64 msk = __ballot(bv == wmax);
    const int l = (int)(__ffsll((unsigned long long)msk) - 1);  // lowest lane = lowest index
    const int bidx = t * 8 + bk;
    const int widx = __builtin_amdgcn_readlane(bidx, l);
    const float wx = __int_as_float(__builtin_amdgcn_readlane(__float_as_int(bx), l));
    const float wy = __int_as_float(__builtin_amdgcn_readlane(__float_as_int(by), l));
    const float wz = __int_as_float(__builtin_amdgcn_readlane(__float_as_int(bz), l));
    const int p = it & 1;
    if (lane == 0) {
      wkey[p][w] = ((u64)__float_as_uint(wmax) << 32) | (u32)(NPT - 1 - widx);
      wcrd[p][w][0] = wx; wcrd[p][w][1] = wy; wcrd[p][w][2] = wz;
    }
    __syncthreads();
    u64 bestk = wkey[p][0]; int bw = 0;
    #pragma unroll
    for (int i = 1; i < 8; ++i) { u64 o = wkey[p][i]; if (o > bestk) { bestk = o; bw = i; } }
    fx = wcrd[p][bw][0]; fy = wcrd[p][bw][1]; fz = wcrd[p][bw][2];
    // buffer p is not rewritten until iteration it+2, which is after barrier(it+1):
    // all reads of p complete before then -> single barrier per iteration is safe.
  }
}

// ---------------- Ball query: one wave per (b,s) pair; DPP u64-min extraction ----------------
#define SQCAP 1024
__global__ __launch_bounds__(256) void k_ball(const float* __restrict__ xyz,
                                              const float* __restrict__ nxyz,
                                              ushort_t* __restrict__ ballidx) {
  __shared__ u64 keys[4][SQCAP];
  const int w = threadIdx.x >> 6, lane = threadIdx.x & 63;
  const int pair = blockIdx.x * 4 + w;
  const int b = pair >> 10;
  const float* xb = xyz + (size_t)b * NPT * 3;
  const float nx = nxyz[(size_t)pair*3+0];
  const float ny = nxyz[(size_t)pair*3+1];
  const float nz = nxyz[(size_t)pair*3+2];
  const float ssn = __fadd_rn(__fadd_rn(__fmul_rn(nx,nx), __fmul_rn(ny,ny)), __fmul_rn(nz,nz));
  int cnt = 0;
  for (int n0 = 0; n0 < NPT; n0 += 64) {
    const int n = n0 + lane;
    const float px = xb[3*n+0], py = xb[3*n+1], pz = xb[3*n+2];
    const float ssx = __fadd_rn(__fadd_rn(__fmul_rn(px,px), __fmul_rn(py,py)), __fmul_rn(pz,pz));
    const float dt  = __fadd_rn(__fadd_rn(__fmul_rn(nx,px), __fmul_rn(ny,py)), __fmul_rn(nz,pz));
    const float d   = __fsub_rn(__fadd_rn(ssn, ssx), __fmul_rn(2.0f, dt));
    const bool in = !(d > 0.04f);   // keep d <= radius^2
    const u64 mask = __ballot(in);
    if (in) {
      int pos = cnt + (int)__popcll(mask & ((1ull << lane) - 1ull));
      if (pos < SQCAP) {
        u32 bits = __float_as_uint(d);
        u32 mapped = (bits & 0x80000000u) ? ~bits : (bits | 0x80000000u); // total order incl. negatives
        keys[w][pos] = ((u64)mapped << 32) | (u32)n;
      }
    }
    cnt += (int)__popcll(mask);
  }
  if (cnt > SQCAP) cnt = SQCAP;
  ushort_t* op = ballidx + (size_t)pair * NK;
  int first = 0;
  volatile u64* kp = &keys[w][0];
  for (int iter = 0; iter < NK; ++iter) {
    if (iter < cnt) {
      u64 mb = ~0ull;
      for (int i = lane; i < cnt; i += 64) { u64 kk = kp[i]; if (kk < mb) mb = kk; }
      mb = wave_min_u64_bcast(mb);
      for (int i = lane; i < cnt; i += 64) { if (kp[i] == mb) kp[i] = ~0ull; }
      const int widx = (int)(mb & 0xffffffffu);
      if (iter == 0) first = widx;
      if (lane == 0) op[iter] = (ushort_t)widx;
    } else {
      if (lane == 0) op[iter] = (ushort_t)first;
    }
  }
}

// ================= shared helpers for conv passes (all f32) =================
template<int ROWS, int K, int LDW>
__device__ __forceinline__ void load_W(float* Ws, const float* __restrict__ W, int t) {
  for (int e = t; e < ROWS * K; e += 256) Ws[(e / K) * LDW + (e % K)] = W[e];
}

__device__ __forceinline__ void gather_X(float (*Xs)[69],
    const float* __restrict__ xyz, const float* __restrict__ points,
    const float* __restrict__ nxyz, const ushort_t* __restrict__ ballidx,
    int bp4, int b, int t) {
  if (t < 128) {
    const int pair = bp4 + (t >> 5);
    const int idx = (int)ballidx[pair * NK + (t & 31)];
    const float* p = xyz + ((size_t)b * NPT + idx) * 3;
    const float* nzp = nxyz + (size_t)pair * 3;
    Xs[t][0] = __fsub_rn(p[0], nzp[0]);
    Xs[t][1] = __fsub_rn(p[1], nzp[1]);
    Xs[t][2] = __fsub_rn(p[2], nzp[2]);
  }
  for (int g = t; g < 2048; g += 256) {
    const int r = g >> 4, ch = g & 15;
    const int pair = bp4 + (r >> 5);
    const int idx = (int)ballidx[pair * NK + (r & 31)];
    float4 v = *(const float4*)(points + ((size_t)b * NPT + idx) * ND + ch * 4);
    Xs[r][3 + ch*4 + 0] = v.x; Xs[r][3 + ch*4 + 1] = v.y;
    Xs[r][3 + ch*4 + 2] = v.z; Xs[r][3 + ch*4 + 3] = v.w;
  }
}

template<int K, int LDW>
__device__ __forceinline__ void gemm4(const float (*Xs)[69], const float* Ws,
                                      const float* __restrict__ bias, int biasOff,
                                      int tr, int tc, float acc[8][4]) {
  #pragma unroll
  for (int j = 0; j < 4; ++j) {
    float bb = bias[biasOff + tc*4 + j];
    #pragma unroll
    for (int i = 0; i < 8; ++i) acc[i][j] = bb;
  }
  for (int c = 0; c < K; ++c) {
    float wv[4];
    #pragma unroll
    for (int j = 0; j < 4; ++j) wv[j] = Ws[(tc*4 + j) * LDW + c];
    #pragma unroll
    for (int i = 0; i < 8; ++i) {
      float xv = Xs[tr*8 + i][c];
      #pragma unroll
      for (int j = 0; j < 4; ++j) acc[i][j] = fmaf(xv, wv[j], acc[i][j]);
    }
  }
}

__device__ __forceinline__ void bn_coef(const float* __restrict__ stats, int base,
    const float* __restrict__ g, const float* __restrict__ bt,
    float* sc, float* sh, int t) {
  if (t < 64) {
    const float inv = 1.0f / CNT_TOTAL;
    float mu = stats[base + t] * inv;
    float var = fmaxf(stats[base + 64 + t] * inv - mu * mu, 0.0f);
    float rs = rsqrtf(var + 1e-5f);
    float s = g[t] * rs;
    sc[t] = s; sh[t] = bt[t] - mu * s;
  }
}

__device__ __forceinline__ void load_y_bn(float (*Xs)[69], const float* __restrict__ y,
    size_t row0, const float* sc, const float* sh, int t) {
  for (int g = t; g < 2048; g += 256) {
    const int r = g >> 4, ch = g & 15;
    float4 v = *(const float4*)(y + (row0 + r) * 64 + ch * 4);
    const int c = ch * 4;
    Xs[r][c+0] = fmaxf(fmaf(sc[c+0], v.x, sh[c+0]), 0.0f);
    Xs[r][c+1] = fmaxf(fmaf(sc[c+1], v.y, sh[c+1]), 0.0f);
    Xs[r][c+2] = fmaxf(fmaf(sc[c+2], v.z, sh[c+2]), 0.0f);
    Xs[r][c+3] = fmaxf(fmaf(sc[c+3], v.w, sh[c+3]), 0.0f);
  }
}

__device__ __forceinline__ void bn_to_Xs(float (*Xs)[69], float acc[8][4],
    const float* sc, const float* sh, int tr, int tc) {
  #pragma unroll
  for (int j = 0; j < 4; ++j) {
    int c = tc*4 + j;
    #pragma unroll
    for (int i = 0; i < 8; ++i)
      Xs[tr*8 + i][c] = fmaxf(fmaf(sc[c], acc[i][j], sh[c]), 0.0f);
  }
}

__device__ __forceinline__ void store_y(float* __restrict__ y, size_t row0,
                                        float acc[8][4], int tr, int tc) {
  #pragma unroll
  for (int i = 0; i < 8; ++i) {
    size_t gr = row0 + tr*8 + i;
    *(float4*)(y + gr * 64 + tc*4) = make_float4(acc[i][0], acc[i][1], acc[i][2], acc[i][3]);
  }
}

__device__ __forceinline__ void stats_acc64(float acc[8][4], float* ssum, float* ssq,
    float* __restrict__ gsum, float* __restrict__ gsq, int tc, int t) {
  #pragma unroll
  for (int j = 0; j < 4; ++j) {
    float s0 = 0.f, s1 = 0.f;
    #pragma unroll
    for (int i = 0; i < 8; ++i) { s0 += acc[i][j]; s1 += acc[i][j]*acc[i][j]; }
    atomicAdd(&ssum[tc*4 + j], s0);
    atomicAdd(&ssq [tc*4 + j], s1);
  }
  __syncthreads();
  if (t < 64) { atomicAdd(&gsum[t], ssum[t]); atomicAdd(&gsq[t], ssq[t]); }
}

// ---------------- pass0: gather + GEMM0 + stats0 (optional y0 store) ----------------
template<bool STORE>
__global__ __launch_bounds__(256) void k_pass0(const float* __restrict__ xyz,
    const float* __restrict__ points, const float* __restrict__ nxyz,
    const ushort_t* __restrict__ ballidx, const float* __restrict__ W0,
    const float* __restrict__ b0, float* __restrict__ y0, float* __restrict__ stats) {
  __shared__ float Xs[128][69];
  __shared__ float Ws[64*69];
  __shared__ float ssum[64], ssq[64];
  const int t = threadIdx.x;
  const int bp4 = blockIdx.x * 4, b = bp4 >> 10;
  const size_t row0 = (size_t)blockIdx.x * 128;
  if (t < 64) { ssum[t] = 0.f; ssq[t] = 0.f; }
  load_W<64,67,69>(Ws, W0, t);
  gather_X(Xs, xyz, points, nxyz, ballidx, bp4, b, t);
  __syncthreads();
  const int tr = t >> 4, tc = t & 15;
  float acc[8][4];
  gemm4<67,69>(Xs, Ws, b0, 0, tr, tc, acc);
  if (STORE) store_y(y0, row0, acc, tr, tc);
  stats_acc64(acc, ssum, ssq, stats, stats + 64, tc, t);
}

// ---------------- pass1: (y0 or recompute) -> BN0 -> GEMM1 + stats1 ----------------
template<bool LOADY0, bool STORE>
__global__ __launch_bounds__(256) void k_pass1(const float* __restrict__ xyz,
    const float* __restrict__ points, const float* __restrict__ nxyz,
    const ushort_t* __restrict__ ballidx,
    const float* __restrict__ W0, const float* __restrict__ b0,
    const float* __restrict__ g0, const float* __restrict__ bt0,
    const float* __restrict__ W1, const float* __restrict__ b1,
    const float* __restrict__ y0, float* __restrict__ y1, float* __restrict__ stats) {
  __shared__ float Xs[128][69];
  __shared__ float Ws[64*69];
  __shared__ float sc[64], sh[64], ssum[64], ssq[64];
  const int t = threadIdx.x;
  const int bp4 = blockIdx.x * 4, b = bp4 >> 10;
  const size_t row0 = (size_t)blockIdx.x * 128;
  if (t < 64) { ssum[t] = 0.f; ssq[t] = 0.f; }
  bn_coef(stats, 0, g0, bt0, sc, sh, t);
  const int tr = t >> 4, tc = t & 15;
  if (LOADY0) {
    load_W<64,64,69>(Ws, W1, t);
    __syncthreads();
    load_y_bn(Xs, y0, row0, sc, sh, t);
    __syncthreads();
  } else {
    load_W<64,67,69>(Ws, W0, t);
    gather_X(Xs, xyz, points, nxyz, ballidx, bp4, b, t);
    __syncthreads();
    float a0[8][4];
    gemm4<67,69>(Xs, Ws, b0, 0, tr, tc, a0);
    __syncthreads();
    bn_to_Xs(Xs, a0, sc, sh, tr, tc);
    load_W<64,64,69>(Ws, W1, t);
    __syncthreads();
  }
  float acc[8][4];
  gemm4<64,69>(Xs, Ws, b1, 0, tr, tc, acc);
  if (STORE) store_y(y1, row0, acc, tr, tc);
  stats_acc64(acc, ssum, ssq, stats + 128, stats + 192, tc, t);
}

// ---- pass2: (y1 / y0 / recompute) -> GEMM2 (two 64-ch halves) + stats2 + pre-BN pool ----
// Pool extremum (max if g2[o]>=0 else min) stored f32 IN PLACE into out's new_points region.
template<int MODE>   // 0 = load y1, 1 = load y0, 2 = recompute all
__global__ __launch_bounds__(256) void k_pass2(const float* __restrict__ xyz,
    const float* __restrict__ points, const float* __restrict__ nxyz,
    const ushort_t* __restrict__ ballidx,
    const float* __restrict__ W0, const float* __restrict__ b0,
    const float* __restrict__ g0, const float* __restrict__ bt0,
    const float* __restrict__ W1, const float* __restrict__ b1,
    const float* __restrict__ g1, const float* __restrict__ bt1,
    const float* __restrict__ W2, const float* __restrict__ b2,
    const float* __restrict__ g2,
    const float* __restrict__ y0, const float* __restrict__ y1,
    float* __restrict__ out, float* __restrict__ stats) {
  __shared__ float Xs[128][69];
  __shared__ float Ws[64*69];      // W0/W1 stages (LDW 69) and W2 halves (LDW 65)
  __shared__ float plex[16*64];
  __shared__ float sc0[64], sh0[64], sc1[64], sh1[64];
  __shared__ float ssum[128], ssq[128], sg[128];
  const int t = threadIdx.x;
  const int bp4 = blockIdx.x * 4, b = bp4 >> 10;
  const size_t row0 = (size_t)blockIdx.x * 128;
  if (t < 128) { ssum[t] = 0.f; ssq[t] = 0.f; sg[t] = g2[t]; }
  bn_coef(stats, 128, g1, bt1, sc1, sh1, t);
  const int tr = t >> 4, tc = t & 15;
  if (MODE == 0) {
    load_y_bn(Xs, y1, row0, sc1, sh1, t);
  } else {
    bn_coef(stats, 0, g0, bt0, sc0, sh0, t);
    if (MODE == 1) {
      load_W<64,64,69>(Ws, W1, t);
      __syncthreads();
      load_y_bn(Xs, y0, row0, sc0, sh0, t);
      __syncthreads();
    } else {
      load_W<64,67,69>(Ws, W0, t);
      gather_X(Xs, xyz, points, nxyz, ballidx, bp4, b, t);
      __syncthreads();
      float a0[8][4];
      gemm4<67,69>(Xs, Ws, b0, 0, tr, tc, a0);
      __syncthreads();
      bn_to_Xs(Xs, a0, sc0, sh0, tr, tc);
      load_W<64,64,69>(Ws, W1, t);
      __syncthreads();
    }
    float a1[8][4];
    gemm4<64,69>(Xs, Ws, b1, 0, tr, tc, a1);
    __syncthreads();
    bn_to_Xs(Xs, a1, sc1, sh1, tr, tc);
  }
  // two 64-channel halves of the N=128 GEMM
  for (int h = 0; h < 2; ++h) {
    load_W<64,64,65>(Ws, W2 + h * 64 * 64, t);
    __syncthreads();                       // Ws + Xs ready (also covers pre-loop Xs writes)
    float acc[8][4];
    gemm4<64,65>(Xs, Ws, b2, h * 64, tr, tc, acc);
    #pragma unroll
    for (int j = 0; j < 4; ++j) {
      float s0 = 0.f, s1 = 0.f;
      #pragma unroll
      for (int i = 0; i < 8; ++i) { s0 += acc[i][j]; s1 += acc[i][j]*acc[i][j]; }
      atomicAdd(&ssum[h*64 + tc*4 + j], s0);
      atomicAdd(&ssq [h*64 + tc*4 + j], s1);
    }
    #pragma unroll
    for (int j = 0; j < 4; ++j) {
      const bool useMax = sg[h*64 + tc*4 + j] >= 0.0f;
      float e = acc[0][j];
      #pragma unroll
      for (int i = 1; i < 8; ++i) e = useMax ? fmaxf(e, acc[i][j]) : fminf(e, acc[i][j]);
      plex[tr * 64 + tc*4 + j] = e;
    }
    __syncthreads();                       // plex complete (all gemms of this half done)
    {
      const int pl = t >> 6, o = t & 63;   // 4 pairs x 64 channels
      const bool useMax = sg[h*64 + o] >= 0.0f;
      float e = plex[(pl*4 + 0) * 64 + o];
      #pragma unroll
      for (int i = 1; i < 4; ++i) {
        float v = plex[(pl*4 + i) * 64 + o];
        e = useMax ? fmaxf(e, v) : fminf(e, v);
      }
      out[OUT_NP_OFF + (size_t)(bp4 + pl) * 128 + h*64 + o] = e;
    }
    // next-half load_W is gated by the top-of-loop __syncthreads
  }
  __syncthreads();
  if (t < 128) { atomicAdd(&stats[256 + t], ssum[t]); atomicAdd(&stats[384 + t], ssq[t]); }
}

// ---------------- final: BN2+ReLU applied in place to pooled extrema ----------------
__global__ __launch_bounds__(256) void k_final(const float* __restrict__ stats,
                                               const float* __restrict__ g2,
                                               const float* __restrict__ bt2,
                                               float* __restrict__ out) {
  const int gid = blockIdx.x * 256 + threadIdx.x;   // < 2097152
  const int o = gid & 127;
  const float inv = 1.0f / CNT_TOTAL;
  float mu = stats[256 + o] * inv;
  float var = fmaxf(stats[384 + o] * inv - mu * mu, 0.0f);
  float rs = rsqrtf(var + 1e-5f);
  float s = g2[o] * rs;
  float b = bt2[o] - mu * s;
  float v = out[OUT_NP_OFF + gid];
  out[OUT_NP_OFF + gid] = fmaxf(fmaf(s, v, b), 0.0f);   // monotone BN+ReLU commutes with pool
}

extern "C" void kernel_launch(void* const* d_in, const int* in_sizes, int n_in,
                              void* d_out, int out_size, void* d_ws, size_t ws_size,
                              hipStream_t stream) {
  (void)in_sizes; (void)n_in; (void)out_size;
  const float* xyz    = (const float*)d_in[0];
  const float* points = (const float*)d_in[1];
  const float* W0  = (const float*)d_in[2];
  const float* b0  = (const float*)d_in[3];
  const float* g0  = (const float*)d_in[4];
  const float* bt0 = (const float*)d_in[5];
  const float* W1  = (const float*)d_in[6];
  const float* b1  = (const float*)d_in[7];
  const float* g1  = (const float*)d_in[8];
  const float* bt1 = (const float*)d_in[9];
  const float* W2  = (const float*)d_in[10];
  const float* b2  = (const float*)d_in[11];
  const float* g2  = (const float*)d_in[12];
  const float* bt2 = (const float*)d_in[13];
  float* out = (float*)d_out;

  // Workspace: stats 2 KB + ballidx 1 MB mandatory; y0/y1 (f32, 134 MB each) only if room.
  const size_t statsB = 2048;
  const size_t ballB  = (size_t)16384 * NK * 2;       // 1,048,576
  const size_t MINWS  = statsB + ballB;               // 1,050,624
  const size_t yB     = (size_t)524288 * 64 * 4;      // 134,217,728

  char* ws = (char*)d_ws;
  float* stats      = (float*)ws;
  ushort_t* ballidx = (ushort_t*)(ws + statsB);
  float* y0         = (float*)(ws + MINWS);
  float* y1         = (float*)(ws + MINWS + yB);

  hipMemsetAsync(stats, 0, statsB, stream);
  k_fps <<<dim3(NB),   dim3(512),  0, stream>>>(xyz, out);
  k_ball<<<dim3(4096), dim3(256),  0, stream>>>(xyz, out, ballidx);

  if (ws_size >= MINWS + 2 * yB) {
    k_pass0<true>        <<<dim3(4096), dim3(256), 0, stream>>>(xyz, points, out, ballidx, W0, b0, y0, stats);
    k_pass1<true, true>  <<<dim3(4096), dim3(256), 0, stream>>>(xyz, points, out, ballidx, W0, b0, g0, bt0, W1, b1, y0, y1, stats);
    k_pass2<0>           <<<dim3(4096), dim3(256), 0, stream>>>(xyz, points, out, ballidx, W0, b0, g0, bt0, W1, b1, g1, bt1, W2, b2, g2, y0, y1, out, stats);
  } else if (ws_size >= MINWS + yB) {
    k_pass0<true>        <<<dim3(4096), dim3(256), 0, stream>>>(xyz, points, out, ballidx, W0, b0, y0, stats);
    k_pass1<true, false> <<<dim3(4096), dim3(256), 0, stream>>>(xyz, points, out, ballidx, W0, b0, g0, bt0, W1, b1, y0, y1, stats);
    k_pass2<1>           <<<dim3(4096), dim3(256), 0, stream>>>(xyz, points, out, ballidx, W0, b0, g0, bt0, W1, b1, g1, bt1, W2, b2, g2, y0, y1, out, stats);
  } else {
    k_pass0<false>       <<<dim3(4096), dim3(256), 0, stream>>>(xyz, points, out, ballidx, W0, b0, y0, stats);
    k_pass1<false, false><<<dim3(4096), dim3(256), 0, stream>>>(xyz, points, out, ballidx, W0, b0, g0, bt0, W1, b1, y0, y1, stats);
    k_pass2<2>           <<<dim3(4096), dim3(256), 0, stream>>>(xyz, points, out, ballidx, W0, b0, g0, bt0, W1, b1, g1, bt1, W2, b2, g2, y0, y1, out, stats);
  }
  k_final<<<dim3(8192), dim3(256), 0, stream>>>(stats, g2, bt2, out);
}

// Round 8
// 1431.816 us; speedup vs baseline: 1.6627x; 1.1970x over previous
//
#include <hip/hip_runtime.h>

typedef unsigned int u32;
typedef unsigned long long u64;
typedef unsigned short ushort_t;

#define NB 16
#define NPT 4096
#define NS 1024
#define NK 32
#define ND 64
#define CNT_TOTAL 524288.0f   // 16*1024*32
#define OUT_NP_OFF 49152      // new_points offset in d_out (f32 elements)

// DPP helpers (CDNA gfx9-lineage row_shr / row_bcast controls; wave64 = 4 rows of 16).
// update_dpp(old=x, src=x, ..., bound_ctrl=false): invalid source lanes keep x (identity).
__device__ __forceinline__ u64 wave_min_u64_bcast(u64 x) {
  #define DPP_MINU64(CTRL) {                                                  \
    int hi = (int)(x >> 32), lo = (int)(u32)x;                                \
    int h2 = __builtin_amdgcn_update_dpp(hi, hi, CTRL, 0xf, 0xf, false);      \
    int l2 = __builtin_amdgcn_update_dpp(lo, lo, CTRL, 0xf, 0xf, false);      \
    u64 y = ((u64)(u32)h2 << 32) | (u32)l2;                                   \
    if (y < x) x = y; }
  DPP_MINU64(0x111) DPP_MINU64(0x112) DPP_MINU64(0x114) DPP_MINU64(0x118)
  DPP_MINU64(0x142) DPP_MINU64(0x143)
  #undef DPP_MINU64
  u32 hi = (u32)__builtin_amdgcn_readlane((int)(x >> 32), 63);
  u32 lo = (u32)__builtin_amdgcn_readlane((int)(u32)x, 63);
  return ((u64)hi << 32) | lo;
}

// f64-key wave max: key = positive double whose bits are (f32bits(d)<<32 | loword).
// Monotone bitwise for positive doubles -> fmax == u64 max, tie-break in loword.
__device__ __forceinline__ double wave_max_f64(double x) {
  #define DPP_MAXF64(CTRL) {                                                  \
    int hi = __double2hiint(x), lo = __double2loint(x);                       \
    int h2 = __builtin_amdgcn_update_dpp(hi, hi, CTRL, 0xf, 0xf, false);      \
    int l2 = __builtin_amdgcn_update_dpp(lo, lo, CTRL, 0xf, 0xf, false);      \
    x = fmax(x, __hiloint2double(h2, l2)); }
  DPP_MAXF64(0x111) DPP_MAXF64(0x112) DPP_MAXF64(0x114) DPP_MAXF64(0x118)
  DPP_MAXF64(0x142) DPP_MAXF64(0x143)
  #undef DPP_MAXF64
  return x;   // lane 63 holds the wave max
}

// ---------------- FPS: one block per batch; 256 thr, 16 pts/thread; f64-key reduce ----------------
__global__ __launch_bounds__(256) void k_fps(const float* __restrict__ xyz,
                                             float* __restrict__ out_xyz) {
  __shared__ float sx[NPT], sy[NPT], sz[NPT];
  __shared__ u64 wkey[2][4];
  const int b = blockIdx.x, t = threadIdx.x;
  const int lane = t & 63, w = t >> 6;
  const float* xb = xyz + (size_t)b * NPT * 3;
  float px[16], py[16], pz[16], dst[16];
  {
    float f[48];
    const float4* s4 = (const float4*)(xb + t * 48);
    #pragma unroll
    for (int j = 0; j < 12; ++j) {
      float4 v = s4[j];
      f[4*j+0] = v.x; f[4*j+1] = v.y; f[4*j+2] = v.z; f[4*j+3] = v.w;
    }
    #pragma unroll
    for (int k = 0; k < 16; ++k) {
      px[k] = f[3*k+0]; py[k] = f[3*k+1]; pz[k] = f[3*k+2]; dst[k] = 1e10f;
      const int n = t * 16 + k;
      sx[n] = px[k]; sy[n] = py[k]; sz[n] = pz[k];
    }
  }
  __syncthreads();
  float fx = xb[0], fy = xb[1], fz = xb[2];   // farthest = index 0 initially
  float* ob = out_xyz + (size_t)b * NS * 3;
  const int lobase = NPT - 1 - t * 16;        // lo word = lobase - k  (unique, >=0)
  for (int it = 0; it < NS; ++it) {
    if (t == 0) { ob[3*it+0] = fx; ob[3*it+1] = fy; ob[3*it+2] = fz; }
    double kk[16];
    // exact numpy order: ((dx*dx + dy*dy) + dz*dz), then minimum-update
    #pragma unroll
    for (int k = 0; k < 16; ++k) {
      float dx = __fsub_rn(px[k], fx), dy = __fsub_rn(py[k], fy), dz = __fsub_rn(pz[k], fz);
      float dd = __fadd_rn(__fadd_rn(__fmul_rn(dx,dx), __fmul_rn(dy,dy)), __fmul_rn(dz,dz));
      dd = fminf(dst[k], dd);
      dst[k] = dd;
      kk[k] = __hiloint2double(__float_as_int(dd), lobase - k);
    }
    // in-thread 4-level max tree (15 x v_max_f64; key max == (max d, min idx))
    #pragma unroll
    for (int s = 8; s >= 1; s >>= 1)
      #pragma unroll
      for (int i = 0; i < 16; ++i) { if (i < s) kk[i] = fmax(kk[i], kk[i + s]); }
    double wm = wave_max_f64(kk[0]);
    const int p = it & 1;
    if (lane == 63) wkey[p][w] = ((u64)(u32)__double2hiint(wm) << 32) | (u32)__double2loint(wm);
    __syncthreads();
    // cross-wave: 4 keys, then uniform coord lookup
    u64 m0 = wkey[p][0], m1 = wkey[p][1], m2 = wkey[p][2], m3 = wkey[p][3];
    u64 ma = m0 > m1 ? m0 : m1, mb = m2 > m3 ? m2 : m3;
    u64 m = ma > mb ? ma : mb;
    const int idx = NPT - 1 - (int)(m & 0xffffffffu);   // always in [0, 4095]
    fx = sx[idx]; fy = sy[idx]; fz = sz[idx];
    // buffer p rewritten at it+2, strictly after barrier(it+1) which follows all reads@it.
  }
}

// ---------------- Ball query: one wave per (b,s) pair; DPP u64-min extraction ----------------
#define SQCAP 1024
__global__ __launch_bounds__(256) void k_ball(const float* __restrict__ xyz,
                                              const float* __restrict__ nxyz,
                                              ushort_t* __restrict__ ballidx) {
  __shared__ u64 keys[4][SQCAP];
  const int w = threadIdx.x >> 6, lane = threadIdx.x & 63;
  const int pair = blockIdx.x * 4 + w;
  const int b = pair >> 10;
  const float* xb = xyz + (size_t)b * NPT * 3;
  const float nx = nxyz[(size_t)pair*3+0];
  const float ny = nxyz[(size_t)pair*3+1];
  const float nz = nxyz[(size_t)pair*3+2];
  const float ssn = __fadd_rn(__fadd_rn(__fmul_rn(nx,nx), __fmul_rn(ny,ny)), __fmul_rn(nz,nz));
  int cnt = 0;
  for (int n0 = 0; n0 < NPT; n0 += 64) {
    const int n = n0 + lane;
    const float px = xb[3*n+0], py = xb[3*n+1], pz = xb[3*n+2];
    const float ssx = __fadd_rn(__fadd_rn(__fmul_rn(px,px), __fmul_rn(py,py)), __fmul_rn(pz,pz));
    const float dt  = __fadd_rn(__fadd_rn(__fmul_rn(nx,px), __fmul_rn(ny,py)), __fmul_rn(nz,pz));
    const float d   = __fsub_rn(__fadd_rn(ssn, ssx), __fmul_rn(2.0f, dt));
    const bool in = !(d > 0.04f);   // keep d <= radius^2
    const u64 mask = __ballot(in);
    if (in) {
      int pos = cnt + (int)__popcll(mask & ((1ull << lane) - 1ull));
      if (pos < SQCAP) {
        u32 bits = __float_as_uint(d);
        u32 mapped = (bits & 0x80000000u) ? ~bits : (bits | 0x80000000u); // total order incl. negatives
        keys[w][pos] = ((u64)mapped << 32) | (u32)n;
      }
    }
    cnt += (int)__popcll(mask);
  }
  if (cnt > SQCAP) cnt = SQCAP;
  ushort_t* op = ballidx + (size_t)pair * NK;
  int first = 0;
  volatile u64* kp = &keys[w][0];
  for (int iter = 0; iter < NK; ++iter) {
    if (iter < cnt) {
      u64 mb = ~0ull;
      for (int i = lane; i < cnt; i += 64) { u64 kk = kp[i]; if (kk < mb) mb = kk; }
      mb = wave_min_u64_bcast(mb);
      for (int i = lane; i < cnt; i += 64) { if (kp[i] == mb) kp[i] = ~0ull; }
      const int widx = (int)(mb & 0xffffffffu);
      if (iter == 0) first = widx;
      if (lane == 0) op[iter] = (ushort_t)widx;
    } else {
      if (lane == 0) op[iter] = (ushort_t)first;
    }
  }
}

// ================= shared helpers for conv passes (all f32) =================
template<int ROWS, int K, int LDW>
__device__ __forceinline__ void load_W(float* Ws, const float* __restrict__ W, int t) {
  for (int e = t; e < ROWS * K; e += 256) Ws[(e / K) * LDW + (e % K)] = W[e];
}

__device__ __forceinline__ void gather_X(float (*Xs)[69],
    const float* __restrict__ xyz, const float* __restrict__ points,
    const float* __restrict__ nxyz, const ushort_t* __restrict__ ballidx,
    int bp4, int b, int t) {
  if (t < 128) {
    const int pair = bp4 + (t >> 5);
    const int idx = (int)ballidx[pair * NK + (t & 31)];
    const float* p = xyz + ((size_t)b * NPT + idx) * 3;
    const float* nzp = nxyz + (size_t)pair * 3;
    Xs[t][0] = __fsub_rn(p[0], nzp[0]);
    Xs[t][1] = __fsub_rn(p[1], nzp[1]);
    Xs[t][2] = __fsub_rn(p[2], nzp[2]);
  }
  for (int g = t; g < 2048; g += 256) {
    const int r = g >> 4, ch = g & 15;
    const int pair = bp4 + (r >> 5);
    const int idx = (int)ballidx[pair * NK + (r & 31)];
    float4 v = *(const float4*)(points + ((size_t)b * NPT + idx) * ND + ch * 4);
    Xs[r][3 + ch*4 + 0] = v.x; Xs[r][3 + ch*4 + 1] = v.y;
    Xs[r][3 + ch*4 + 2] = v.z; Xs[r][3 + ch*4 + 3] = v.w;
  }
}

template<int K, int LDW>
__device__ __forceinline__ void gemm4(const float (*Xs)[69], const float* Ws,
                                      const float* __restrict__ bias, int biasOff,
                                      int tr, int tc, float acc[8][4]) {
  #pragma unroll
  for (int j = 0; j < 4; ++j) {
    float bb = bias[biasOff + tc*4 + j];
    #pragma unroll
    for (int i = 0; i < 8; ++i) acc[i][j] = bb;
  }
  for (int c = 0; c < K; ++c) {
    float wv[4];
    #pragma unroll
    for (int j = 0; j < 4; ++j) wv[j] = Ws[(tc*4 + j) * LDW + c];
    #pragma unroll
    for (int i = 0; i < 8; ++i) {
      float xv = Xs[tr*8 + i][c];
      #pragma unroll
      for (int j = 0; j < 4; ++j) acc[i][j] = fmaf(xv, wv[j], acc[i][j]);
    }
  }
}

__device__ __forceinline__ void bn_coef(const float* __restrict__ stats, int base,
    const float* __restrict__ g, const float* __restrict__ bt,
    float* sc, float* sh, int t) {
  if (t < 64) {
    const float inv = 1.0f / CNT_TOTAL;
    float mu = stats[base + t] * inv;
    float var = fmaxf(stats[base + 64 + t] * inv - mu * mu, 0.0f);
    float rs = rsqrtf(var + 1e-5f);
    float s = g[t] * rs;
    sc[t] = s; sh[t] = bt[t] - mu * s;
  }
}

__device__ __forceinline__ void load_y_bn(float (*Xs)[69], const float* __restrict__ y,
    size_t row0, const float* sc, const float* sh, int t) {
  for (int g = t; g < 2048; g += 256) {
    const int r = g >> 4, ch = g & 15;
    float4 v = *(const float4*)(y + (row0 + r) * 64 + ch * 4);
    const int c = ch * 4;
    Xs[r][c+0] = fmaxf(fmaf(sc[c+0], v.x, sh[c+0]), 0.0f);
    Xs[r][c+1] = fmaxf(fmaf(sc[c+1], v.y, sh[c+1]), 0.0f);
    Xs[r][c+2] = fmaxf(fmaf(sc[c+2], v.z, sh[c+2]), 0.0f);
    Xs[r][c+3] = fmaxf(fmaf(sc[c+3], v.w, sh[c+3]), 0.0f);
  }
}

__device__ __forceinline__ void bn_to_Xs(float (*Xs)[69], float acc[8][4],
    const float* sc, const float* sh, int tr, int tc) {
  #pragma unroll
  for (int j = 0; j < 4; ++j) {
    int c = tc*4 + j;
    #pragma unroll
    for (int i = 0; i < 8; ++i)
      Xs[tr*8 + i][c] = fmaxf(fmaf(sc[c], acc[i][j], sh[c]), 0.0f);
  }
}

__device__ __forceinline__ void store_y(float* __restrict__ y, size_t row0,
                                        float acc[8][4], int tr, int tc) {
  #pragma unroll
  for (int i = 0; i < 8; ++i) {
    size_t gr = row0 + tr*8 + i;
    *(float4*)(y + gr * 64 + tc*4) = make_float4(acc[i][0], acc[i][1], acc[i][2], acc[i][3]);
  }
}

__device__ __forceinline__ void stats_acc64(float acc[8][4], float* ssum, float* ssq,
    float* __restrict__ gsum, float* __restrict__ gsq, int tc, int t) {
  #pragma unroll
  for (int j = 0; j < 4; ++j) {
    float s0 = 0.f, s1 = 0.f;
    #pragma unroll
    for (int i = 0; i < 8; ++i) { s0 += acc[i][j]; s1 += acc[i][j]*acc[i][j]; }
    atomicAdd(&ssum[tc*4 + j], s0);
    atomicAdd(&ssq [tc*4 + j], s1);
  }
  __syncthreads();
  if (t < 64) { atomicAdd(&gsum[t], ssum[t]); atomicAdd(&gsq[t], ssq[t]); }
}

// ---------------- pass0: gather + GEMM0 + stats0 (optional y0 store) ----------------
template<bool STORE>
__global__ __launch_bounds__(256) void k_pass0(const float* __restrict__ xyz,
    const float* __restrict__ points, const float* __restrict__ nxyz,
    const ushort_t* __restrict__ ballidx, const float* __restrict__ W0,
    const float* __restrict__ b0, float* __restrict__ y0, float* __restrict__ stats) {
  __shared__ float Xs[128][69];
  __shared__ float Ws[64*69];
  __shared__ float ssum[64], ssq[64];
  const int t = threadIdx.x;
  const int bp4 = blockIdx.x * 4, b = bp4 >> 10;
  const size_t row0 = (size_t)blockIdx.x * 128;
  if (t < 64) { ssum[t] = 0.f; ssq[t] = 0.f; }
  load_W<64,67,69>(Ws, W0, t);
  gather_X(Xs, xyz, points, nxyz, ballidx, bp4, b, t);
  __syncthreads();
  const int tr = t >> 4, tc = t & 15;
  float acc[8][4];
  gemm4<67,69>(Xs, Ws, b0, 0, tr, tc, acc);
  if (STORE) store_y(y0, row0, acc, tr, tc);
  stats_acc64(acc, ssum, ssq, stats, stats + 64, tc, t);
}

// ---------------- pass1: (y0 or recompute) -> BN0 -> GEMM1 + stats1 ----------------
template<bool LOADY0, bool STORE>
__global__ __launch_bounds__(256) void k_pass1(const float* __restrict__ xyz,
    const float* __restrict__ points, const float* __restrict__ nxyz,
    const ushort_t* __restrict__ ballidx,
    const float* __restrict__ W0, const float* __restrict__ b0,
    const float* __restrict__ g0, const float* __restrict__ bt0,
    const float* __restrict__ W1, const float* __restrict__ b1,
    const float* __restrict__ y0, float* __restrict__ y1, float* __restrict__ stats) {
  __shared__ float Xs[128][69];
  __shared__ float Ws[64*69];
  __shared__ float sc[64], sh[64], ssum[64], ssq[64];
  const int t = threadIdx.x;
  const int bp4 = blockIdx.x * 4, b = bp4 >> 10;
  const size_t row0 = (size_t)blockIdx.x * 128;
  if (t < 64) { ssum[t] = 0.f; ssq[t] = 0.f; }
  bn_coef(stats, 0, g0, bt0, sc, sh, t);
  const int tr = t >> 4, tc = t & 15;
  if (LOADY0) {
    load_W<64,64,69>(Ws, W1, t);
    __syncthreads();
    load_y_bn(Xs, y0, row0, sc, sh, t);
    __syncthreads();
  } else {
    load_W<64,67,69>(Ws, W0, t);
    gather_X(Xs, xyz, points, nxyz, ballidx, bp4, b, t);
    __syncthreads();
    float a0[8][4];
    gemm4<67,69>(Xs, Ws, b0, 0, tr, tc, a0);
    __syncthreads();
    bn_to_Xs(Xs, a0, sc, sh, tr, tc);
    load_W<64,64,69>(Ws, W1, t);
    __syncthreads();
  }
  float acc[8][4];
  gemm4<64,69>(Xs, Ws, b1, 0, tr, tc, acc);
  if (STORE) store_y(y1, row0, acc, tr, tc);
  stats_acc64(acc, ssum, ssq, stats + 128, stats + 192, tc, t);
}

// ---- pass2: (y1 / y0 / recompute) -> GEMM2 (two 64-ch halves) + stats2 + pre-BN pool ----
// Pool extremum (max if g2[o]>=0 else min) stored f32 IN PLACE into out's new_points region.
template<int MODE>   // 0 = load y1, 1 = load y0, 2 = recompute all
__global__ __launch_bounds__(256) void k_pass2(const float* __restrict__ xyz,
    const float* __restrict__ points, const float* __restrict__ nxyz,
    const ushort_t* __restrict__ ballidx,
    const float* __restrict__ W0, const float* __restrict__ b0,
    const float* __restrict__ g0, const float* __restrict__ bt0,
    const float* __restrict__ W1, const float* __restrict__ b1,
    const float* __restrict__ g1, const float* __restrict__ bt1,
    const float* __restrict__ W2, const float* __restrict__ b2,
    const float* __restrict__ g2,
    const float* __restrict__ y0, const float* __restrict__ y1,
    float* __restrict__ out, float* __restrict__ stats) {
  __shared__ float Xs[128][69];
  __shared__ float Ws[64*69];      // W0/W1 stages (LDW 69) and W2 halves (LDW 65)
  __shared__ float plex[16*64];
  __shared__ float sc0[64], sh0[64], sc1[64], sh1[64];
  __shared__ float ssum[128], ssq[128], sg[128];
  const int t = threadIdx.x;
  const int bp4 = blockIdx.x * 4, b = bp4 >> 10;
  const size_t row0 = (size_t)blockIdx.x * 128;
  if (t < 128) { ssum[t] = 0.f; ssq[t] = 0.f; sg[t] = g2[t]; }
  bn_coef(stats, 128, g1, bt1, sc1, sh1, t);
  const int tr = t >> 4, tc = t & 15;
  if (MODE == 0) {
    load_y_bn(Xs, y1, row0, sc1, sh1, t);
  } else {
    bn_coef(stats, 0, g0, bt0, sc0, sh0, t);
    if (MODE == 1) {
      load_W<64,64,69>(Ws, W1, t);
      __syncthreads();
      load_y_bn(Xs, y0, row0, sc0, sh0, t);
      __syncthreads();
    } else {
      load_W<64,67,69>(Ws, W0, t);
      gather_X(Xs, xyz, points, nxyz, ballidx, bp4, b, t);
      __syncthreads();
      float a0[8][4];
      gemm4<67,69>(Xs, Ws, b0, 0, tr, tc, a0);
      __syncthreads();
      bn_to_Xs(Xs, a0, sc0, sh0, tr, tc);
      load_W<64,64,69>(Ws, W1, t);
      __syncthreads();
    }
    float a1[8][4];
    gemm4<64,69>(Xs, Ws, b1, 0, tr, tc, a1);
    __syncthreads();
    bn_to_Xs(Xs, a1, sc1, sh1, tr, tc);
  }
  // two 64-channel halves of the N=128 GEMM
  for (int h = 0; h < 2; ++h) {
    load_W<64,64,65>(Ws, W2 + h * 64 * 64, t);
    __syncthreads();                       // Ws + Xs ready (also covers pre-loop Xs writes)
    float acc[8][4];
    gemm4<64,65>(Xs, Ws, b2, h * 64, tr, tc, acc);
    #pragma unroll
    for (int j = 0; j < 4; ++j) {
      float s0 = 0.f, s1 = 0.f;
      #pragma unroll
      for (int i = 0; i < 8; ++i) { s0 += acc[i][j]; s1 += acc[i][j]*acc[i][j]; }
      atomicAdd(&ssum[h*64 + tc*4 + j], s0);
      atomicAdd(&ssq [h*64 + tc*4 + j], s1);
    }
    #pragma unroll
    for (int j = 0; j < 4; ++j) {
      const bool useMax = sg[h*64 + tc*4 + j] >= 0.0f;
      float e = acc[0][j];
      #pragma unroll
      for (int i = 1; i < 8; ++i) e = useMax ? fmaxf(e, acc[i][j]) : fminf(e, acc[i][j]);
      plex[tr * 64 + tc*4 + j] = e;
    }
    __syncthreads();                       // plex complete (all gemms of this half done)
    {
      const int pl = t >> 6, o = t & 63;   // 4 pairs x 64 channels
      const bool useMax = sg[h*64 + o] >= 0.0f;
      float e = plex[(pl*4 + 0) * 64 + o];
      #pragma unroll
      for (int i = 1; i < 4; ++i) {
        float v = plex[(pl*4 + i) * 64 + o];
        e = useMax ? fmaxf(e, v) : fminf(e, v);
      }
      out[OUT_NP_OFF + (size_t)(bp4 + pl) * 128 + h*64 + o] = e;
    }
    // next-half load_W is gated by the top-of-loop __syncthreads
  }
  __syncthreads();
  if (t < 128) { atomicAdd(&stats[256 + t], ssum[t]); atomicAdd(&stats[384 + t], ssq[t]); }
}

// ---------------- final: BN2+ReLU applied in place to pooled extrema ----------------
__global__ __launch_bounds__(256) void k_final(const float* __restrict__ stats,
                                               const float* __restrict__ g2,
                                               const float* __restrict__ bt2,
                                               float* __restrict__ out) {
  const int gid = blockIdx.x * 256 + threadIdx.x;   // < 2097152
  const int o = gid & 127;
  const float inv = 1.0f / CNT_TOTAL;
  float mu = stats[256 + o] * inv;
  float var = fmaxf(stats[384 + o] * inv - mu * mu, 0.0f);
  float rs = rsqrtf(var + 1e-5f);
  float s = g2[o] * rs;
  float b = bt2[o] - mu * s;
  float v = out[OUT_NP_OFF + gid];
  out[OUT_NP_OFF + gid] = fmaxf(fmaf(s, v, b), 0.0f);   // monotone BN+ReLU commutes with pool
}

extern "C" void kernel_launch(void* const* d_in, const int* in_sizes, int n_in,
                              void* d_out, int out_size, void* d_ws, size_t ws_size,
                              hipStream_t stream) {
  (void)in_sizes; (void)n_in; (void)out_size;
  const float* xyz    = (const float*)d_in[0];
  const float* points = (const float*)d_in[1];
  const float* W0  = (const float*)d_in[2];
  const float* b0  = (const float*)d_in[3];
  const float* g0  = (const float*)d_in[4];
  const float* bt0 = (const float*)d_in[5];
  const float* W1  = (const float*)d_in[6];
  const float* b1  = (const float*)d_in[7];
  const float* g1  = (const float*)d_in[8];
  const float* bt1 = (const float*)d_in[9];
  const float* W2  = (const float*)d_in[10];
  const float* b2  = (const float*)d_in[11];
  const float* g2  = (const float*)d_in[12];
  const float* bt2 = (const float*)d_in[13];
  float* out = (float*)d_out;

  // Workspace: stats 2 KB + ballidx 1 MB mandatory; y0/y1 (f32, 134 MB each) only if room.
  const size_t statsB = 2048;
  const size_t ballB  = (size_t)16384 * NK * 2;       // 1,048,576
  const size_t MINWS  = statsB + ballB;               // 1,050,624
  const size_t yB     = (size_t)524288 * 64 * 4;      // 134,217,728

  char* ws = (char*)d_ws;
  float* stats      = (float*)ws;
  ushort_t* ballidx = (ushort_t*)(ws + statsB);
  float* y0         = (float*)(ws + MINWS);
  float* y1         = (float*)(ws + MINWS + yB);

  hipMemsetAsync(stats, 0, statsB, stream);
  k_fps <<<dim3(NB),   dim3(256),  0, stream>>>(xyz, out);
  k_ball<<<dim3(4096), dim3(256),  0, stream>>>(xyz, out, ballidx);

  if (ws_size >= MINWS + 2 * yB) {
    k_pass0<true>        <<<dim3(4096), dim3(256), 0, stream>>>(xyz, points, out, ballidx, W0, b0, y0, stats);
    k_pass1<true, true>  <<<dim3(4096), dim3(256), 0, stream>>>(xyz, points, out, ballidx, W0, b0, g0, bt0, W1, b1, y0, y1, stats);
    k_pass2<0>           <<<dim3(4096), dim3(256), 0, stream>>>(xyz, points, out, ballidx, W0, b0, g0, bt0, W1, b1, g1, bt1, W2, b2, g2, y0, y1, out, stats);
  } else if (ws_size >= MINWS + yB) {
    k_pass0<true>        <<<dim3(4096), dim3(256), 0, stream>>>(xyz, points, out, ballidx, W0, b0, y0, stats);
    k_pass1<true, false> <<<dim3(4096), dim3(256), 0, stream>>>(xyz, points, out, ballidx, W0, b0, g0, bt0, W1, b1, y0, y1, stats);
    k_pass2<1>           <<<dim3(4096), dim3(256), 0, stream>>>(xyz, points, out, ballidx, W0, b0, g0, bt0, W1, b1, g1, bt1, W2, b2, g2, y0, y1, out, stats);
  } else {
    k_pass0<false>       <<<dim3(4096), dim3(256), 0, stream>>>(xyz, points, out, ballidx, W0, b0, y0, stats);
    k_pass1<false, false><<<dim3(4096), dim3(256), 0, stream>>>(xyz, points, out, ballidx, W0, b0, g0, bt0, W1, b1, y0, y1, stats);
    k_pass2<2>           <<<dim3(4096), dim3(256), 0, stream>>>(xyz, points, out, ballidx, W0, b0, g0, bt0, W1, b1, g1, bt1, W2, b2, g2, y0, y1, out, stats);
  }
  k_final<<<dim3(8192), dim3(256), 0, stream>>>(stats, g2, bt2, out);
}

// Round 9
// 1423.405 us; speedup vs baseline: 1.6726x; 1.0059x over previous
//
#include <hip/hip_runtime.h>

typedef unsigned int u32;
typedef unsigned long long u64;
typedef unsigned short ushort_t;

#define NB 16
#define NPT 4096
#define NS 1024
#define NK 32
#define ND 64
#define CNT_TOTAL 524288.0f   // 16*1024*32
#define OUT_NP_OFF 49152      // new_points offset in d_out (f32 elements)

// DPP helpers (CDNA gfx9-lineage row_shr / row_bcast controls; wave64 = 4 rows of 16).
__device__ __forceinline__ u64 wave_min_u64_bcast(u64 x) {
  #define DPP_MINU64(CTRL) {                                                  \
    int hi = (int)(x >> 32), lo = (int)(u32)x;                                \
    int h2 = __builtin_amdgcn_update_dpp(hi, hi, CTRL, 0xf, 0xf, false);      \
    int l2 = __builtin_amdgcn_update_dpp(lo, lo, CTRL, 0xf, 0xf, false);      \
    u64 y = ((u64)(u32)h2 << 32) | (u32)l2;                                   \
    if (y < x) x = y; }
  DPP_MINU64(0x111) DPP_MINU64(0x112) DPP_MINU64(0x114) DPP_MINU64(0x118)
  DPP_MINU64(0x142) DPP_MINU64(0x143)
  #undef DPP_MINU64
  u32 hi = (u32)__builtin_amdgcn_readlane((int)(x >> 32), 63);
  u32 lo = (u32)__builtin_amdgcn_readlane((int)(u32)x, 63);
  return ((u64)hi << 32) | lo;
}

// f64-key wave max: key = positive double, bits = (f32bits(d)<<32 | loword).
// Monotone bitwise for positive doubles -> fmax == u64 max, tie-break in loword.
__device__ __forceinline__ double wave_max_f64(double x) {
  #define DPP_MAXF64(CTRL) {                                                  \
    int hi = __double2hiint(x), lo = __double2loint(x);                       \
    int h2 = __builtin_amdgcn_update_dpp(hi, hi, CTRL, 0xf, 0xf, false);      \
    int l2 = __builtin_amdgcn_update_dpp(lo, lo, CTRL, 0xf, 0xf, false);      \
    x = fmax(x, __hiloint2double(h2, l2)); }
  DPP_MAXF64(0x111) DPP_MAXF64(0x112) DPP_MAXF64(0x114) DPP_MAXF64(0x118)
  DPP_MAXF64(0x142) DPP_MAXF64(0x143)
  #undef DPP_MAXF64
  return x;   // lane 63 holds the wave max
}

// ---------------- FPS: one block per batch; 512 thr (2 waves/SIMD), 8 pts/thread ----------------
__global__ __launch_bounds__(512) void k_fps(const float* __restrict__ xyz,
                                             float* __restrict__ out_xyz) {
  __shared__ float sx[NPT], sy[NPT], sz[NPT];
  __shared__ u64 wkey[2][8];
  const int b = blockIdx.x, t = threadIdx.x;
  const int lane = t & 63, w = t >> 6;
  const float* xb = xyz + (size_t)b * NPT * 3;
  float px[8], py[8], pz[8], dst[8];
  {
    const float4* s4 = (const float4*)(xb + t * 24);
    float4 v0 = s4[0], v1 = s4[1], v2 = s4[2], v3 = s4[3], v4 = s4[4], v5 = s4[5];
    px[0]=v0.x; py[0]=v0.y; pz[0]=v0.z;  px[1]=v0.w; py[1]=v1.x; pz[1]=v1.y;
    px[2]=v1.z; py[2]=v1.w; pz[2]=v2.x;  px[3]=v2.y; py[3]=v2.z; pz[3]=v2.w;
    px[4]=v3.x; py[4]=v3.y; pz[4]=v3.z;  px[5]=v3.w; py[5]=v4.x; pz[5]=v4.y;
    px[6]=v4.z; py[6]=v4.w; pz[6]=v5.x;  px[7]=v5.y; py[7]=v5.z; pz[7]=v5.w;
    #pragma unroll
    for (int k = 0; k < 8; ++k) {
      const int n = t * 8 + k;
      sx[n] = px[k]; sy[n] = py[k]; sz[n] = pz[k];
      dst[k] = 1e10f;
    }
  }
  __syncthreads();
  float fx = xb[0], fy = xb[1], fz = xb[2];   // farthest = index 0 initially
  float* ob = out_xyz + (size_t)b * NS * 3;
  const int lobase = NPT - 1 - t * 8;         // lo word = lobase - k (unique, >= 0)
  for (int it = 0; it < NS; ++it) {
    if (t == 0) { ob[3*it+0] = fx; ob[3*it+1] = fy; ob[3*it+2] = fz; }
    double kk[8];
    // exact numpy order: ((dx*dx + dy*dy) + dz*dz), then minimum-update
    #pragma unroll
    for (int k = 0; k < 8; ++k) {
      float dx = __fsub_rn(px[k], fx), dy = __fsub_rn(py[k], fy), dz = __fsub_rn(pz[k], fz);
      float dd = __fadd_rn(__fadd_rn(__fmul_rn(dx,dx), __fmul_rn(dy,dy)), __fmul_rn(dz,dz));
      dd = fminf(dst[k], dd);
      dst[k] = dd;
      kk[k] = __hiloint2double(__float_as_int(dd), lobase - k);
    }
    // in-thread 3-level max tree (7 x v_max_f64; key max == (max d, min idx))
    #pragma unroll
    for (int s = 4; s >= 1; s >>= 1)
      #pragma unroll
      for (int i = 0; i < 4; ++i) { if (i < s) kk[i] = fmax(kk[i], kk[i + s]); }
    double wm = wave_max_f64(kk[0]);
    const int p = it & 1;
    if (lane == 63) wkey[p][w] = ((u64)(u32)__double2hiint(wm) << 32) | (u32)__double2loint(wm);
    __syncthreads();
    u64 m = wkey[p][0];
    #pragma unroll
    for (int i = 1; i < 8; ++i) { u64 o = wkey[p][i]; if (o > m) m = o; }
    const int idx = NPT - 1 - (int)(m & 0xffffffffu);   // always in [0, 4095]
    fx = sx[idx]; fy = sy[idx]; fz = sz[idx];
    // buffer p rewritten at it+2, strictly after barrier(it+1) which follows all reads@it.
  }
}

// ---------------- Ball query: one wave per (b,s) pair; register-cached extraction ----------------
#define SQCAP 1024
__global__ __launch_bounds__(256) void k_ball(const float* __restrict__ xyz,
                                              const float* __restrict__ nxyz,
                                              ushort_t* __restrict__ ballidx) {
  __shared__ u64 keys[4][SQCAP];
  const int w = threadIdx.x >> 6, lane = threadIdx.x & 63;
  const int pair = blockIdx.x * 4 + w;
  const int b = pair >> 10;
  const float* xb = xyz + (size_t)b * NPT * 3;
  const float nx = nxyz[(size_t)pair*3+0];
  const float ny = nxyz[(size_t)pair*3+1];
  const float nz = nxyz[(size_t)pair*3+2];
  const float ssn = __fadd_rn(__fadd_rn(__fmul_rn(nx,nx), __fmul_rn(ny,ny)), __fmul_rn(nz,nz));
  int cnt = 0;
  for (int n0 = 0; n0 < NPT; n0 += 64) {
    const int n = n0 + lane;
    const float px = xb[3*n+0], py = xb[3*n+1], pz = xb[3*n+2];
    const float ssx = __fadd_rn(__fadd_rn(__fmul_rn(px,px), __fmul_rn(py,py)), __fmul_rn(pz,pz));
    const float dt  = __fadd_rn(__fadd_rn(__fmul_rn(nx,px), __fmul_rn(ny,py)), __fmul_rn(nz,pz));
    const float d   = __fsub_rn(__fadd_rn(ssn, ssx), __fmul_rn(2.0f, dt));
    const bool in = !(d > 0.04f);   // keep d <= radius^2
    const u64 mask = __ballot(in);
    if (in) {
      int pos = cnt + (int)__popcll(mask & ((1ull << lane) - 1ull));
      if (pos < SQCAP) {
        u32 bits = __float_as_uint(d);
        u32 mapped = (bits & 0x80000000u) ? ~bits : (bits | 0x80000000u); // total order incl. negatives
        keys[w][pos] = ((u64)mapped << 32) | (u32)n;
      }
    }
    cnt += (int)__popcll(mask);
  }
  if (cnt > SQCAP) cnt = SQCAP;
  ushort_t* op = ballidx + (size_t)pair * NK;
  int first = 0;
  if (cnt <= 192) {
    // keys held in registers; unique keys -> exactly one slot invalidates per iter
    u64 r0 = (lane       < cnt) ? keys[w][lane      ] : ~0ull;
    u64 r1 = (lane + 64  < cnt) ? keys[w][lane +  64] : ~0ull;
    u64 r2 = (lane + 128 < cnt) ? keys[w][lane + 128] : ~0ull;
    for (int iter = 0; iter < NK; ++iter) {
      if (iter < cnt) {
        u64 mb = r0 < r1 ? r0 : r1; if (r2 < mb) mb = r2;
        mb = wave_min_u64_bcast(mb);
        if (r0 == mb) r0 = ~0ull;
        if (r1 == mb) r1 = ~0ull;
        if (r2 == mb) r2 = ~0ull;
        const int widx = (int)(mb & 0xffffffffu);
        if (iter == 0) first = widx;
        if (lane == 0) op[iter] = (ushort_t)widx;
      } else {
        if (lane == 0) op[iter] = (ushort_t)first;
      }
    }
  } else {
    volatile u64* kp = &keys[w][0];
    for (int iter = 0; iter < NK; ++iter) {
      if (iter < cnt) {
        u64 mb = ~0ull;
        for (int i = lane; i < cnt; i += 64) { u64 kk = kp[i]; if (kk < mb) mb = kk; }
        mb = wave_min_u64_bcast(mb);
        for (int i = lane; i < cnt; i += 64) { if (kp[i] == mb) kp[i] = ~0ull; }
        const int widx = (int)(mb & 0xffffffffu);
        if (iter == 0) first = widx;
        if (lane == 0) op[iter] = (ushort_t)widx;
      } else {
        if (lane == 0) op[iter] = (ushort_t)first;
      }
    }
  }
}

// ================= shared helpers for conv passes (all f32) =================
template<int ROWS, int K, int LDW>
__device__ __forceinline__ void load_W(float* Ws, const float* __restrict__ W, int t) {
  for (int e = t; e < ROWS * K; e += 256) Ws[(e / K) * LDW + (e % K)] = W[e];
}

__device__ __forceinline__ void gather_X(float (*Xs)[69],
    const float* __restrict__ xyz, const float* __restrict__ points,
    const float* __restrict__ nxyz, const ushort_t* __restrict__ ballidx,
    int bp4, int b, int t) {
  if (t < 128) {
    const int pair = bp4 + (t >> 5);
    const int idx = (int)ballidx[pair * NK + (t & 31)];
    const float* p = xyz + ((size_t)b * NPT + idx) * 3;
    const float* nzp = nxyz + (size_t)pair * 3;
    Xs[t][0] = __fsub_rn(p[0], nzp[0]);
    Xs[t][1] = __fsub_rn(p[1], nzp[1]);
    Xs[t][2] = __fsub_rn(p[2], nzp[2]);
  }
  for (int g = t; g < 2048; g += 256) {
    const int r = g >> 4, ch = g & 15;
    const int pair = bp4 + (r >> 5);
    const int idx = (int)ballidx[pair * NK + (r & 31)];
    float4 v = *(const float4*)(points + ((size_t)b * NPT + idx) * ND + ch * 4);
    Xs[r][3 + ch*4 + 0] = v.x; Xs[r][3 + ch*4 + 1] = v.y;
    Xs[r][3 + ch*4 + 2] = v.z; Xs[r][3 + ch*4 + 3] = v.w;
  }
}

template<int K, int LDW>
__device__ __forceinline__ void gemm4(const float (*Xs)[69], const float* Ws,
                                      const float* __restrict__ bias, int biasOff,
                                      int tr, int tc, float acc[8][4]) {
  #pragma unroll
  for (int j = 0; j < 4; ++j) {
    float bb = bias[biasOff + tc*4 + j];
    #pragma unroll
    for (int i = 0; i < 8; ++i) acc[i][j] = bb;
  }
  for (int c = 0; c < K; ++c) {
    float wv[4];
    #pragma unroll
    for (int j = 0; j < 4; ++j) wv[j] = Ws[(tc*4 + j) * LDW + c];
    #pragma unroll
    for (int i = 0; i < 8; ++i) {
      float xv = Xs[tr*8 + i][c];
      #pragma unroll
      for (int j = 0; j < 4; ++j) acc[i][j] = fmaf(xv, wv[j], acc[i][j]);
    }
  }
}

__device__ __forceinline__ void bn_coef(const float* __restrict__ stats, int base,
    const float* __restrict__ g, const float* __restrict__ bt,
    float* sc, float* sh, int t) {
  if (t < 64) {
    const float inv = 1.0f / CNT_TOTAL;
    float mu = stats[base + t] * inv;
    float var = fmaxf(stats[base + 64 + t] * inv - mu * mu, 0.0f);
    float rs = rsqrtf(var + 1e-5f);
    float s = g[t] * rs;
    sc[t] = s; sh[t] = bt[t] - mu * s;
  }
}

__device__ __forceinline__ void load_y_bn(float (*Xs)[69], const float* __restrict__ y,
    size_t row0, const float* sc, const float* sh, int t) {
  for (int g = t; g < 2048; g += 256) {
    const int r = g >> 4, ch = g & 15;
    float4 v = *(const float4*)(y + (row0 + r) * 64 + ch * 4);
    const int c = ch * 4;
    Xs[r][c+0] = fmaxf(fmaf(sc[c+0], v.x, sh[c+0]), 0.0f);
    Xs[r][c+1] = fmaxf(fmaf(sc[c+1], v.y, sh[c+1]), 0.0f);
    Xs[r][c+2] = fmaxf(fmaf(sc[c+2], v.z, sh[c+2]), 0.0f);
    Xs[r][c+3] = fmaxf(fmaf(sc[c+3], v.w, sh[c+3]), 0.0f);
  }
}

__device__ __forceinline__ void bn_to_Xs(float (*Xs)[69], float acc[8][4],
    const float* sc, const float* sh, int tr, int tc) {
  #pragma unroll
  for (int j = 0; j < 4; ++j) {
    int c = tc*4 + j;
    #pragma unroll
    for (int i = 0; i < 8; ++i)
      Xs[tr*8 + i][c] = fmaxf(fmaf(sc[c], acc[i][j], sh[c]), 0.0f);
  }
}

__device__ __forceinline__ void store_y(float* __restrict__ y, size_t row0,
                                        float acc[8][4], int tr, int tc) {
  #pragma unroll
  for (int i = 0; i < 8; ++i) {
    size_t gr = row0 + tr*8 + i;
    *(float4*)(y + gr * 64 + tc*4) = make_float4(acc[i][0], acc[i][1], acc[i][2], acc[i][3]);
  }
}

__device__ __forceinline__ void stats_acc64(float acc[8][4], float* ssum, float* ssq,
    float* __restrict__ gsum, float* __restrict__ gsq, int tc, int t) {
  #pragma unroll
  for (int j = 0; j < 4; ++j) {
    float s0 = 0.f, s1 = 0.f;
    #pragma unroll
    for (int i = 0; i < 8; ++i) { s0 += acc[i][j]; s1 += acc[i][j]*acc[i][j]; }
    atomicAdd(&ssum[tc*4 + j], s0);
    atomicAdd(&ssq [tc*4 + j], s1);
  }
  __syncthreads();
  if (t < 64) { atomicAdd(&gsum[t], ssum[t]); atomicAdd(&gsq[t], ssq[t]); }
}

// ---------------- pass0: gather + GEMM0 + stats0 (optional y0 store) ----------------
template<bool STORE>
__global__ __launch_bounds__(256) void k_pass0(const float* __restrict__ xyz,
    const float* __restrict__ points, const float* __restrict__ nxyz,
    const ushort_t* __restrict__ ballidx, const float* __restrict__ W0,
    const float* __restrict__ b0, float* __restrict__ y0, float* __restrict__ stats) {
  __shared__ float Xs[128][69];
  __shared__ float Ws[64*69];
  __shared__ float ssum[64], ssq[64];
  const int t = threadIdx.x;
  const int bp4 = blockIdx.x * 4, b = bp4 >> 10;
  const size_t row0 = (size_t)blockIdx.x * 128;
  if (t < 64) { ssum[t] = 0.f; ssq[t] = 0.f; }
  load_W<64,67,69>(Ws, W0, t);
  gather_X(Xs, xyz, points, nxyz, ballidx, bp4, b, t);
  __syncthreads();
  const int tr = t >> 4, tc = t & 15;
  float acc[8][4];
  gemm4<67,69>(Xs, Ws, b0, 0, tr, tc, acc);
  if (STORE) store_y(y0, row0, acc, tr, tc);
  stats_acc64(acc, ssum, ssq, stats, stats + 64, tc, t);
}

// ---------------- pass1: (y0 or recompute) -> BN0 -> GEMM1 + stats1 ----------------
template<bool LOADY0, bool STORE>
__global__ __launch_bounds__(256) void k_pass1(const float* __restrict__ xyz,
    const float* __restrict__ points, const float* __restrict__ nxyz,
    const ushort_t* __restrict__ ballidx,
    const float* __restrict__ W0, const float* __restrict__ b0,
    const float* __restrict__ g0, const float* __restrict__ bt0,
    const float* __restrict__ W1, const float* __restrict__ b1,
    const float* __restrict__ y0, float* __restrict__ y1, float* __restrict__ stats) {
  __shared__ float Xs[128][69];
  __shared__ float Ws[64*69];
  __shared__ float sc[64], sh[64], ssum[64], ssq[64];
  const int t = threadIdx.x;
  const int bp4 = blockIdx.x * 4, b = bp4 >> 10;
  const size_t row0 = (size_t)blockIdx.x * 128;
  if (t < 64) { ssum[t] = 0.f; ssq[t] = 0.f; }
  bn_coef(stats, 0, g0, bt0, sc, sh, t);
  const int tr = t >> 4, tc = t & 15;
  if (LOADY0) {
    load_W<64,64,69>(Ws, W1, t);
    __syncthreads();
    load_y_bn(Xs, y0, row0, sc, sh, t);
    __syncthreads();
  } else {
    load_W<64,67,69>(Ws, W0, t);
    gather_X(Xs, xyz, points, nxyz, ballidx, bp4, b, t);
    __syncthreads();
    float a0[8][4];
    gemm4<67,69>(Xs, Ws, b0, 0, tr, tc, a0);
    __syncthreads();
    bn_to_Xs(Xs, a0, sc, sh, tr, tc);
    load_W<64,64,69>(Ws, W1, t);
    __syncthreads();
  }
  float acc[8][4];
  gemm4<64,69>(Xs, Ws, b1, 0, tr, tc, acc);
  if (STORE) store_y(y1, row0, acc, tr, tc);
  stats_acc64(acc, ssum, ssq, stats + 128, stats + 192, tc, t);
}

// ---- pass2: (y1 / y0 / recompute) -> GEMM2 (two 64-ch halves) + stats2 + pre-BN pool ----
// Pool extremum (max if g2[o]>=0 else min) stored f32 IN PLACE into out's new_points region.
template<int MODE>   // 0 = load y1, 1 = load y0, 2 = recompute all
__global__ __launch_bounds__(256) void k_pass2(const float* __restrict__ xyz,
    const float* __restrict__ points, const float* __restrict__ nxyz,
    const ushort_t* __restrict__ ballidx,
    const float* __restrict__ W0, const float* __restrict__ b0,
    const float* __restrict__ g0, const float* __restrict__ bt0,
    const float* __restrict__ W1, const float* __restrict__ b1,
    const float* __restrict__ g1, const float* __restrict__ bt1,
    const float* __restrict__ W2, const float* __restrict__ b2,
    const float* __restrict__ g2,
    const float* __restrict__ y0, const float* __restrict__ y1,
    float* __restrict__ out, float* __restrict__ stats) {
  __shared__ float Xs[128][69];
  __shared__ float Ws[64*69];      // W0/W1 stages (LDW 69) and W2 halves (LDW 65)
  __shared__ float plex[16*64];
  __shared__ float sc0[64], sh0[64], sc1[64], sh1[64];
  __shared__ float ssum[128], ssq[128], sg[128];
  const int t = threadIdx.x;
  const int bp4 = blockIdx.x * 4, b = bp4 >> 10;
  const size_t row0 = (size_t)blockIdx.x * 128;
  if (t < 128) { ssum[t] = 0.f; ssq[t] = 0.f; sg[t] = g2[t]; }
  bn_coef(stats, 128, g1, bt1, sc1, sh1, t);
  const int tr = t >> 4, tc = t & 15;
  if (MODE == 0) {
    load_y_bn(Xs, y1, row0, sc1, sh1, t);
  } else {
    bn_coef(stats, 0, g0, bt0, sc0, sh0, t);
    if (MODE == 1) {
      load_W<64,64,69>(Ws, W1, t);
      __syncthreads();
      load_y_bn(Xs, y0, row0, sc0, sh0, t);
      __syncthreads();
    } else {
      load_W<64,67,69>(Ws, W0, t);
      gather_X(Xs, xyz, points, nxyz, ballidx, bp4, b, t);
      __syncthreads();
      float a0[8][4];
      gemm4<67,69>(Xs, Ws, b0, 0, tr, tc, a0);
      __syncthreads();
      bn_to_Xs(Xs, a0, sc0, sh0, tr, tc);
      load_W<64,64,69>(Ws, W1, t);
      __syncthreads();
    }
    float a1[8][4];
    gemm4<64,69>(Xs, Ws, b1, 0, tr, tc, a1);
    __syncthreads();
    bn_to_Xs(Xs, a1, sc1, sh1, tr, tc);
  }
  // two 64-channel halves of the N=128 GEMM
  for (int h = 0; h < 2; ++h) {
    load_W<64,64,65>(Ws, W2 + h * 64 * 64, t);
    __syncthreads();                       // Ws + Xs ready (also covers pre-loop Xs writes)
    float acc[8][4];
    gemm4<64,65>(Xs, Ws, b2, h * 64, tr, tc, acc);
    #pragma unroll
    for (int j = 0; j < 4; ++j) {
      float s0 = 0.f, s1 = 0.f;
      #pragma unroll
      for (int i = 0; i < 8; ++i) { s0 += acc[i][j]; s1 += acc[i][j]*acc[i][j]; }
      atomicAdd(&ssum[h*64 + tc*4 + j], s0);
      atomicAdd(&ssq [h*64 + tc*4 + j], s1);
    }
    #pragma unroll
    for (int j = 0; j < 4; ++j) {
      const bool useMax = sg[h*64 + tc*4 + j] >= 0.0f;
      float e = acc[0][j];
      #pragma unroll
      for (int i = 1; i < 8; ++i) e = useMax ? fmaxf(e, acc[i][j]) : fminf(e, acc[i][j]);
      plex[tr * 64 + tc*4 + j] = e;
    }
    __syncthreads();                       // plex complete (all gemms of this half done)
    {
      const int pl = t >> 6, o = t & 63;   // 4 pairs x 64 channels
      const bool useMax = sg[h*64 + o] >= 0.0f;
      float e = plex[(pl*4 + 0) * 64 + o];
      #pragma unroll
      for (int i = 1; i < 4; ++i) {
        float v = plex[(pl*4 + i) * 64 + o];
        e = useMax ? fmaxf(e, v) : fminf(e, v);
      }
      out[OUT_NP_OFF + (size_t)(bp4 + pl) * 128 + h*64 + o] = e;
    }
    // next-half load_W is gated by the top-of-loop __syncthreads
  }
  __syncthreads();
  if (t < 128) { atomicAdd(&stats[256 + t], ssum[t]); atomicAdd(&stats[384 + t], ssq[t]); }
}

// ---------------- final: BN2+ReLU applied in place to pooled extrema ----------------
__global__ __launch_bounds__(256) void k_final(const float* __restrict__ stats,
                                               const float* __restrict__ g2,
                                               const float* __restrict__ bt2,
                                               float* __restrict__ out) {
  const int gid = blockIdx.x * 256 + threadIdx.x;   // < 2097152
  const int o = gid & 127;
  const float inv = 1.0f / CNT_TOTAL;
  float mu = stats[256 + o] * inv;
  float var = fmaxf(stats[384 + o] * inv - mu * mu, 0.0f);
  float rs = rsqrtf(var + 1e-5f);
  float s = g2[o] * rs;
  float b = bt2[o] - mu * s;
  float v = out[OUT_NP_OFF + gid];
  out[OUT_NP_OFF + gid] = fmaxf(fmaf(s, v, b), 0.0f);   // monotone BN+ReLU commutes with pool
}

extern "C" void kernel_launch(void* const* d_in, const int* in_sizes, int n_in,
                              void* d_out, int out_size, void* d_ws, size_t ws_size,
                              hipStream_t stream) {
  (void)in_sizes; (void)n_in; (void)out_size;
  const float* xyz    = (const float*)d_in[0];
  const float* points = (const float*)d_in[1];
  const float* W0  = (const float*)d_in[2];
  const float* b0  = (const float*)d_in[3];
  const float* g0  = (const float*)d_in[4];
  const float* bt0 = (const float*)d_in[5];
  const float* W1  = (const float*)d_in[6];
  const float* b1  = (const float*)d_in[7];
  const float* g1  = (const float*)d_in[8];
  const float* bt1 = (const float*)d_in[9];
  const float* W2  = (const float*)d_in[10];
  const float* b2  = (const float*)d_in[11];
  const float* g2  = (const float*)d_in[12];
  const float* bt2 = (const float*)d_in[13];
  float* out = (float*)d_out;

  // Workspace: stats 2 KB + ballidx 1 MB mandatory; y0/y1 (f32, 134 MB each) only if room.
  const size_t statsB = 2048;
  const size_t ballB  = (size_t)16384 * NK * 2;       // 1,048,576
  const size_t MINWS  = statsB + ballB;               // 1,050,624
  const size_t yB     = (size_t)524288 * 64 * 4;      // 134,217,728

  char* ws = (char*)d_ws;
  float* stats      = (float*)ws;
  ushort_t* ballidx = (ushort_t*)(ws + statsB);
  float* y0         = (float*)(ws + MINWS);
  float* y1         = (float*)(ws + MINWS + yB);

  hipMemsetAsync(stats, 0, statsB, stream);
  k_fps <<<dim3(NB),   dim3(512),  0, stream>>>(xyz, out);
  k_ball<<<dim3(4096), dim3(256),  0, stream>>>(xyz, out, ballidx);

  if (ws_size >= MINWS + 2 * yB) {
    k_pass0<true>        <<<dim3(4096), dim3(256), 0, stream>>>(xyz, points, out, ballidx, W0, b0, y0, stats);
    k_pass1<true, true>  <<<dim3(4096), dim3(256), 0, stream>>>(xyz, points, out, ballidx, W0, b0, g0, bt0, W1, b1, y0, y1, stats);
    k_pass2<0>           <<<dim3(4096), dim3(256), 0, stream>>>(xyz, points, out, ballidx, W0, b0, g0, bt0, W1, b1, g1, bt1, W2, b2, g2, y0, y1, out, stats);
  } else if (ws_size >= MINWS + yB) {
    k_pass0<true>        <<<dim3(4096), dim3(256), 0, stream>>>(xyz, points, out, ballidx, W0, b0, y0, stats);
    k_pass1<true, false> <<<dim3(4096), dim3(256), 0, stream>>>(xyz, points, out, ballidx, W0, b0, g0, bt0, W1, b1, y0, y1, stats);
    k_pass2<1>           <<<dim3(4096), dim3(256), 0, stream>>>(xyz, points, out, ballidx, W0, b0, g0, bt0, W1, b1, g1, bt1, W2, b2, g2, y0, y1, out, stats);
  } else {
    k_pass0<false>       <<<dim3(4096), dim3(256), 0, stream>>>(xyz, points, out, ballidx, W0, b0, y0, stats);
    k_pass1<false, false><<<dim3(4096), dim3(256), 0, stream>>>(xyz, points, out, ballidx, W0, b0, g0, bt0, W1, b1, y0, y1, stats);
    k_pass2<2>           <<<dim3(4096), dim3(256), 0, stream>>>(xyz, points, out, ballidx, W0, b0, g0, bt0, W1, b1, g1, bt1, W2, b2, g2, y0, y1, out, stats);
  }
  k_final<<<dim3(8192), dim3(256), 0, stream>>>(stats, g2, bt2, out);
}

// Round 11
// 1310.684 us; speedup vs baseline: 1.8164x; 1.0860x over previous
//
#include <hip/hip_runtime.h>

typedef unsigned int u32;
typedef unsigned long long u64;
typedef unsigned short ushort_t;

#define NB 16
#define NPT 4096
#define NS 1024
#define NK 32
#define ND 64
#define CNT_TOTAL 524288.0f   // 16*1024*32
#define OUT_NP_OFF 49152      // new_points offset in d_out (f32 elements)

// DPP helpers (CDNA gfx9-lineage row_shr / row_bcast controls; wave64 = 4 rows of 16).
__device__ __forceinline__ u64 wave_min_u64_bcast(u64 x) {
  #define DPP_MINU64(CTRL) {                                                  \
    int hi = (int)(x >> 32), lo = (int)(u32)x;                                \
    int h2 = __builtin_amdgcn_update_dpp(hi, hi, CTRL, 0xf, 0xf, false);      \
    int l2 = __builtin_amdgcn_update_dpp(lo, lo, CTRL, 0xf, 0xf, false);      \
    u64 y = ((u64)(u32)h2 << 32) | (u32)l2;                                   \
    if (y < x) x = y; }
  DPP_MINU64(0x111) DPP_MINU64(0x112) DPP_MINU64(0x114) DPP_MINU64(0x118)
  DPP_MINU64(0x142) DPP_MINU64(0x143)
  #undef DPP_MINU64
  u32 hi = (u32)__builtin_amdgcn_readlane((int)(x >> 32), 63);
  u32 lo = (u32)__builtin_amdgcn_readlane((int)(u32)x, 63);
  return ((u64)hi << 32) | lo;
}

// f64-key wave max: key = positive double, bits = (f32bits(d)<<32 | loword).
// Monotone bitwise for positive doubles -> fmax == u64 max, tie-break in loword.
__device__ __forceinline__ double wave_max_f64(double x) {
  #define DPP_MAXF64(CTRL) {                                                  \
    int hi = __double2hiint(x), lo = __double2loint(x);                       \
    int h2 = __builtin_amdgcn_update_dpp(hi, hi, CTRL, 0xf, 0xf, false);      \
    int l2 = __builtin_amdgcn_update_dpp(lo, lo, CTRL, 0xf, 0xf, false);      \
    x = fmax(x, __hiloint2double(h2, l2)); }
  DPP_MAXF64(0x111) DPP_MAXF64(0x112) DPP_MAXF64(0x114) DPP_MAXF64(0x118)
  DPP_MAXF64(0x142) DPP_MAXF64(0x143)
  #undef DPP_MAXF64
  return x;   // lane 63 holds the wave max
}

// ---------------- FPS: one block per batch; 256 thr, 16 pts/thread; f64-key reduce ----------------
// (R8 version — fastest measured: 568 us)
__global__ __launch_bounds__(256) void k_fps(const float* __restrict__ xyz,
                                             float* __restrict__ out_xyz) {
  __shared__ float sx[NPT], sy[NPT], sz[NPT];
  __shared__ u64 wkey[2][4];
  const int b = blockIdx.x, t = threadIdx.x;
  const int lane = t & 63, w = t >> 6;
  const float* xb = xyz + (size_t)b * NPT * 3;
  float px[16], py[16], pz[16], dst[16];
  {
    float f[48];
    const float4* s4 = (const float4*)(xb + t * 48);
    #pragma unroll
    for (int j = 0; j < 12; ++j) {
      float4 v = s4[j];
      f[4*j+0] = v.x; f[4*j+1] = v.y; f[4*j+2] = v.z; f[4*j+3] = v.w;
    }
    #pragma unroll
    for (int k = 0; k < 16; ++k) {
      px[k] = f[3*k+0]; py[k] = f[3*k+1]; pz[k] = f[3*k+2]; dst[k] = 1e10f;
      const int n = t * 16 + k;
      sx[n] = px[k]; sy[n] = py[k]; sz[n] = pz[k];
    }
  }
  __syncthreads();
  float fx = xb[0], fy = xb[1], fz = xb[2];   // farthest = index 0 initially
  float* ob = out_xyz + (size_t)b * NS * 3;
  const int lobase = NPT - 1 - t * 16;        // lo word = lobase - k  (unique, >=0)
  for (int it = 0; it < NS; ++it) {
    if (t == 0) { ob[3*it+0] = fx; ob[3*it+1] = fy; ob[3*it+2] = fz; }
    double kk[16];
    // exact numpy order: ((dx*dx + dy*dy) + dz*dz), then minimum-update
    #pragma unroll
    for (int k = 0; k < 16; ++k) {
      float dx = __fsub_rn(px[k], fx), dy = __fsub_rn(py[k], fy), dz = __fsub_rn(pz[k], fz);
      float dd = __fadd_rn(__fadd_rn(__fmul_rn(dx,dx), __fmul_rn(dy,dy)), __fmul_rn(dz,dz));
      dd = fminf(dst[k], dd);
      dst[k] = dd;
      kk[k] = __hiloint2double(__float_as_int(dd), lobase - k);
    }
    // in-thread 4-level max tree (15 x v_max_f64; key max == (max d, min idx))
    #pragma unroll
    for (int s = 8; s >= 1; s >>= 1)
      #pragma unroll
      for (int i = 0; i < 16; ++i) { if (i < s) kk[i] = fmax(kk[i], kk[i + s]); }
    double wm = wave_max_f64(kk[0]);
    const int p = it & 1;
    if (lane == 63) wkey[p][w] = ((u64)(u32)__double2hiint(wm) << 32) | (u32)__double2loint(wm);
    __syncthreads();
    // cross-wave: 4 keys, then uniform coord lookup
    u64 m0 = wkey[p][0], m1 = wkey[p][1], m2 = wkey[p][2], m3 = wkey[p][3];
    u64 ma = m0 > m1 ? m0 : m1, mb = m2 > m3 ? m2 : m3;
    u64 m = ma > mb ? ma : mb;
    const int idx = NPT - 1 - (int)(m & 0xffffffffu);   // always in [0, 4095]
    fx = sx[idx]; fy = sy[idx]; fz = sz[idx];
    // buffer p rewritten at it+2, strictly after barrier(it+1) which follows all reads@it.
  }
}

// ---------------- Ball query: one wave per (b,s) pair; register-cached extraction ----------------
#define SQCAP 1024
__global__ __launch_bounds__(256) void k_ball(const float* __restrict__ xyz,
                                              const float* __restrict__ nxyz,
                                              ushort_t* __restrict__ ballidx) {
  __shared__ u64 keys[4][SQCAP];
  const int w = threadIdx.x >> 6, lane = threadIdx.x & 63;
  const int pair = blockIdx.x * 4 + w;
  const int b = pair >> 10;
  const float* xb = xyz + (size_t)b * NPT * 3;
  const float nx = nxyz[(size_t)pair*3+0];
  const float ny = nxyz[(size_t)pair*3+1];
  const float nz = nxyz[(size_t)pair*3+2];
  const float ssn = __fadd_rn(__fadd_rn(__fmul_rn(nx,nx), __fmul_rn(ny,ny)), __fmul_rn(nz,nz));
  int cnt = 0;
  for (int n0 = 0; n0 < NPT; n0 += 64) {
    const int n = n0 + lane;
    const float px = xb[3*n+0], py = xb[3*n+1], pz = xb[3*n+2];
    const float ssx = __fadd_rn(__fadd_rn(__fmul_rn(px,px), __fmul_rn(py,py)), __fmul_rn(pz,pz));
    const float dt  = __fadd_rn(__fadd_rn(__fmul_rn(nx,px), __fmul_rn(ny,py)), __fmul_rn(nz,pz));
    const float d   = __fsub_rn(__fadd_rn(ssn, ssx), __fmul_rn(2.0f, dt));
    const bool in = !(d > 0.04f);   // keep d <= radius^2
    const u64 mask = __ballot(in);
    if (in) {
      int pos = cnt + (int)__popcll(mask & ((1ull << lane) - 1ull));
      if (pos < SQCAP) {
        u32 bits = __float_as_uint(d);
        u32 mapped = (bits & 0x80000000u) ? ~bits : (bits | 0x80000000u); // total order incl. negatives
        keys[w][pos] = ((u64)mapped << 32) | (u32)n;
      }
    }
    cnt += (int)__popcll(mask);
  }
  if (cnt > SQCAP) cnt = SQCAP;
  ushort_t* op = ballidx + (size_t)pair * NK;
  int first = 0;
  if (cnt <= 192) {
    // keys held in registers; unique keys -> exactly one slot invalidates per iter
    u64 r0 = (lane       < cnt) ? keys[w][lane      ] : ~0ull;
    u64 r1 = (lane + 64  < cnt) ? keys[w][lane +  64] : ~0ull;
    u64 r2 = (lane + 128 < cnt) ? keys[w][lane + 128] : ~0ull;
    for (int iter = 0; iter < NK; ++iter) {
      if (iter < cnt) {
        u64 mb = r0 < r1 ? r0 : r1; if (r2 < mb) mb = r2;
        mb = wave_min_u64_bcast(mb);
        if (r0 == mb) r0 = ~0ull;
        if (r1 == mb) r1 = ~0ull;
        if (r2 == mb) r2 = ~0ull;
        const int widx = (int)(mb & 0xffffffffu);
        if (iter == 0) first = widx;
        if (lane == 0) op[iter] = (ushort_t)widx;
      } else {
        if (lane == 0) op[iter] = (ushort_t)first;
      }
    }
  } else {
    volatile u64* kp = &keys[w][0];
    for (int iter = 0; iter < NK; ++iter) {
      if (iter < cnt) {
        u64 mb = ~0ull;
        for (int i = lane; i < cnt; i += 64) { u64 kk = kp[i]; if (kk < mb) mb = kk; }
        mb = wave_min_u64_bcast(mb);
        for (int i = lane; i < cnt; i += 64) { if (kp[i] == mb) kp[i] = ~0ull; }
        const int widx = (int)(mb & 0xffffffffu);
        if (iter == 0) first = widx;
        if (lane == 0) op[iter] = (ushort_t)widx;
      } else {
        if (lane == 0) op[iter] = (ushort_t)first;
      }
    }
  }
}

// ================= shared helpers for conv passes (all f32) =================
template<int ROWS, int K, int LDW>
__device__ __forceinline__ void load_W(float* Ws, const float* __restrict__ W, int t) {
  for (int e = t; e < ROWS * K; e += 256) Ws[(e / K) * LDW + (e % K)] = W[e];
}

__device__ __forceinline__ void gather_X(float (*Xs)[69],
    const float* __restrict__ xyz, const float* __restrict__ points,
    const float* __restrict__ nxyz, const ushort_t* __restrict__ ballidx,
    int bp4, int b, int t) {
  if (t < 128) {
    const int pair = bp4 + (t >> 5);
    const int idx = (int)ballidx[pair * NK + (t & 31)];
    const float* p = xyz + ((size_t)b * NPT + idx) * 3;
    const float* nzp = nxyz + (size_t)pair * 3;
    Xs[t][0] = __fsub_rn(p[0], nzp[0]);
    Xs[t][1] = __fsub_rn(p[1], nzp[1]);
    Xs[t][2] = __fsub_rn(p[2], nzp[2]);
  }
  for (int g = t; g < 2048; g += 256) {
    const int r = g >> 4, ch = g & 15;
    const int pair = bp4 + (r >> 5);
    const int idx = (int)ballidx[pair * NK + (r & 31)];
    float4 v = *(const float4*)(points + ((size_t)b * NPT + idx) * ND + ch * 4);
    Xs[r][3 + ch*4 + 0] = v.x; Xs[r][3 + ch*4 + 1] = v.y;
    Xs[r][3 + ch*4 + 2] = v.z; Xs[r][3 + ch*4 + 3] = v.w;
  }
}

template<int K, int LDW>
__device__ __forceinline__ void gemm4(const float (*Xs)[69], const float* Ws,
                                      const float* __restrict__ bias, int biasOff,
                                      int tr, int tc, float acc[8][4]) {
  #pragma unroll
  for (int j = 0; j < 4; ++j) {
    float bb = bias[biasOff + tc*4 + j];
    #pragma unroll
    for (int i = 0; i < 8; ++i) acc[i][j] = bb;
  }
  for (int c = 0; c < K; ++c) {
    float wv[4];
    #pragma unroll
    for (int j = 0; j < 4; ++j) wv[j] = Ws[(tc*4 + j) * LDW + c];
    #pragma unroll
    for (int i = 0; i < 8; ++i) {
      float xv = Xs[tr*8 + i][c];
      #pragma unroll
      for (int j = 0; j < 4; ++j) acc[i][j] = fmaf(xv, wv[j], acc[i][j]);
    }
  }
}

__device__ __forceinline__ void bn_coef(const float* __restrict__ stats, int base,
    const float* __restrict__ g, const float* __restrict__ bt,
    float* sc, float* sh, int t) {
  if (t < 64) {
    const float inv = 1.0f / CNT_TOTAL;
    float mu = stats[base + t] * inv;
    float var = fmaxf(stats[base + 64 + t] * inv - mu * mu, 0.0f);
    float rs = rsqrtf(var + 1e-5f);
    float s = g[t] * rs;
    sc[t] = s; sh[t] = bt[t] - mu * s;
  }
}

__device__ __forceinline__ void load_y_bn(float (*Xs)[69], const float* y,
    size_t row0, const float* sc, const float* sh, int t) {
  for (int g = t; g < 2048; g += 256) {
    const int r = g >> 4, ch = g & 15;
    float4 v = *(const float4*)(y + (row0 + r) * 64 + ch * 4);
    const int c = ch * 4;
    Xs[r][c+0] = fmaxf(fmaf(sc[c+0], v.x, sh[c+0]), 0.0f);
    Xs[r][c+1] = fmaxf(fmaf(sc[c+1], v.y, sh[c+1]), 0.0f);
    Xs[r][c+2] = fmaxf(fmaf(sc[c+2], v.z, sh[c+2]), 0.0f);
    Xs[r][c+3] = fmaxf(fmaf(sc[c+3], v.w, sh[c+3]), 0.0f);
  }
}

__device__ __forceinline__ void bn_to_Xs(float (*Xs)[69], float acc[8][4],
    const float* sc, const float* sh, int tr, int tc) {
  #pragma unroll
  for (int j = 0; j < 4; ++j) {
    int c = tc*4 + j;
    #pragma unroll
    for (int i = 0; i < 8; ++i)
      Xs[tr*8 + i][c] = fmaxf(fmaf(sc[c], acc[i][j], sh[c]), 0.0f);
  }
}

__device__ __forceinline__ void store_y(float* y, size_t row0,
                                        float acc[8][4], int tr, int tc) {
  #pragma unroll
  for (int i = 0; i < 8; ++i) {
    size_t gr = row0 + tr*8 + i;
    *(float4*)(y + gr * 64 + tc*4) = make_float4(acc[i][0], acc[i][1], acc[i][2], acc[i][3]);
  }
}

__device__ __forceinline__ void stats_acc64(float acc[8][4], float* ssum, float* ssq,
    float* __restrict__ gsum, float* __restrict__ gsq, int tc, int t) {
  #pragma unroll
  for (int j = 0; j < 4; ++j) {
    float s0 = 0.f, s1 = 0.f;
    #pragma unroll
    for (int i = 0; i < 8; ++i) { s0 += acc[i][j]; s1 += acc[i][j]*acc[i][j]; }
    atomicAdd(&ssum[tc*4 + j], s0);
    atomicAdd(&ssq [tc*4 + j], s1);
  }
  __syncthreads();
  if (t < 64) { atomicAdd(&gsum[t], ssum[t]); atomicAdd(&gsq[t], ssq[t]); }
}

// ---------------- pass0: gather + GEMM0 + stats0 (optional y0 store) ----------------
template<bool STORE>
__global__ __launch_bounds__(256) void k_pass0(const float* __restrict__ xyz,
    const float* __restrict__ points, const float* __restrict__ nxyz,
    const ushort_t* __restrict__ ballidx, const float* __restrict__ W0,
    const float* __restrict__ b0, float* __restrict__ y0, float* __restrict__ stats) {
  __shared__ float Xs[128][69];
  __shared__ float Ws[64*69];
  __shared__ float ssum[64], ssq[64];
  const int t = threadIdx.x;
  const int bp4 = blockIdx.x * 4, b = bp4 >> 10;
  const size_t row0 = (size_t)blockIdx.x * 128;
  if (t < 64) { ssum[t] = 0.f; ssq[t] = 0.f; }
  load_W<64,67,69>(Ws, W0, t);
  gather_X(Xs, xyz, points, nxyz, ballidx, bp4, b, t);
  __syncthreads();
  const int tr = t >> 4, tc = t & 15;
  float acc[8][4];
  gemm4<67,69>(Xs, Ws, b0, 0, tr, tc, acc);
  if (STORE) store_y(y0, row0, acc, tr, tc);
  stats_acc64(acc, ssum, ssq, stats, stats + 64, tc, t);
}

// ---------------- pass1: (y0 or recompute) -> BN0 -> GEMM1 + stats1 ----------------
// NOTE: y0 / y1 may alias (in-place ping) — no __restrict__ on them. In-place is safe:
// all y0 rows are read into LDS before the barrier; stores happen after the gemm.
template<bool LOADY0, bool STORE>
__global__ __launch_bounds__(256) void k_pass1(const float* __restrict__ xyz,
    const float* __restrict__ points, const float* __restrict__ nxyz,
    const ushort_t* __restrict__ ballidx,
    const float* __restrict__ W0, const float* __restrict__ b0,
    const float* __restrict__ g0, const float* __restrict__ bt0,
    const float* __restrict__ W1, const float* __restrict__ b1,
    const float* y0, float* y1, float* __restrict__ stats) {
  __shared__ float Xs[128][69];
  __shared__ float Ws[64*69];
  __shared__ float sc[64], sh[64], ssum[64], ssq[64];
  const int t = threadIdx.x;
  const int bp4 = blockIdx.x * 4, b = bp4 >> 10;
  const size_t row0 = (size_t)blockIdx.x * 128;
  if (t < 64) { ssum[t] = 0.f; ssq[t] = 0.f; }
  bn_coef(stats, 0, g0, bt0, sc, sh, t);
  const int tr = t >> 4, tc = t & 15;
  if (LOADY0) {
    load_W<64,64,69>(Ws, W1, t);
    __syncthreads();                       // covers Ws AND sc/sh writes
    load_y_bn(Xs, y0, row0, sc, sh, t);
    __syncthreads();
  } else {
    load_W<64,67,69>(Ws, W0, t);
    gather_X(Xs, xyz, points, nxyz, ballidx, bp4, b, t);
    __syncthreads();
    float a0[8][4];
    gemm4<67,69>(Xs, Ws, b0, 0, tr, tc, a0);
    __syncthreads();
    bn_to_Xs(Xs, a0, sc, sh, tr, tc);
    load_W<64,64,69>(Ws, W1, t);
    __syncthreads();
  }
  float acc[8][4];
  gemm4<64,69>(Xs, Ws, b1, 0, tr, tc, acc);
  if (STORE) store_y(y1, row0, acc, tr, tc);
  stats_acc64(acc, ssum, ssq, stats + 128, stats + 192, tc, t);
}

// ---- pass2: (y1 / recompute) -> GEMM2 (two 64-ch halves) + stats2 + pre-BN pool ----
// Pool extremum (max if g2[o]>=0 else min) stored f32 IN PLACE into out's new_points region.
template<int MODE>   // 0 = load y1, 2 = recompute all
__global__ __launch_bounds__(256) void k_pass2(const float* __restrict__ xyz,
    const float* __restrict__ points, const float* __restrict__ nxyz,
    const ushort_t* __restrict__ ballidx,
    const float* __restrict__ W0, const float* __restrict__ b0,
    const float* __restrict__ g0, const float* __restrict__ bt0,
    const float* __restrict__ W1, const float* __restrict__ b1,
    const float* __restrict__ g1, const float* __restrict__ bt1,
    const float* __restrict__ W2, const float* __restrict__ b2,
    const float* __restrict__ g2,
    const float* y1,
    float* __restrict__ out, float* __restrict__ stats) {
  __shared__ float Xs[128][69];
  __shared__ float Ws[64*69];      // W0/W1 stages (LDW 69) and W2 halves (LDW 65)
  __shared__ float plex[16*64];
  __shared__ float sc0[64], sh0[64], sc1[64], sh1[64];
  __shared__ float ssum[128], ssq[128], sg[128];
  const int t = threadIdx.x;
  const int bp4 = blockIdx.x * 4, b = bp4 >> 10;
  const size_t row0 = (size_t)blockIdx.x * 128;
  if (t < 128) { ssum[t] = 0.f; ssq[t] = 0.f; sg[t] = g2[t]; }
  bn_coef(stats, 128, g1, bt1, sc1, sh1, t);
  const int tr = t >> 4, tc = t & 15;
  if (MODE == 0) {
    __syncthreads();   // FIX: sc1/sh1 written by t<64 must be visible to ALL waves
    load_y_bn(Xs, y1, row0, sc1, sh1, t);
  } else {
    bn_coef(stats, 0, g0, bt0, sc0, sh0, t);
    load_W<64,67,69>(Ws, W0, t);
    gather_X(Xs, xyz, points, nxyz, ballidx, bp4, b, t);
    __syncthreads();
    float a0[8][4];
    gemm4<67,69>(Xs, Ws, b0, 0, tr, tc, a0);
    __syncthreads();
    bn_to_Xs(Xs, a0, sc0, sh0, tr, tc);
    load_W<64,64,69>(Ws, W1, t);
    __syncthreads();
    float a1[8][4];
    gemm4<64,69>(Xs, Ws, b1, 0, tr, tc, a1);
    __syncthreads();
    bn_to_Xs(Xs, a1, sc1, sh1, tr, tc);
  }
  // two 64-channel halves of the N=128 GEMM
  for (int h = 0; h < 2; ++h) {
    load_W<64,64,65>(Ws, W2 + h * 64 * 64, t);
    __syncthreads();                       // Ws + Xs ready (also covers pre-loop Xs writes)
    float acc[8][4];
    gemm4<64,65>(Xs, Ws, b2, h * 64, tr, tc, acc);
    #pragma unroll
    for (int j = 0; j < 4; ++j) {
      float s0 = 0.f, s1 = 0.f;
      #pragma unroll
      for (int i = 0; i < 8; ++i) { s0 += acc[i][j]; s1 += acc[i][j]*acc[i][j]; }
      atomicAdd(&ssum[h*64 + tc*4 + j], s0);
      atomicAdd(&ssq [h*64 + tc*4 + j], s1);
    }
    #pragma unroll
    for (int j = 0; j < 4; ++j) {
      const bool useMax = sg[h*64 + tc*4 + j] >= 0.0f;
      float e = acc[0][j];
      #pragma unroll
      for (int i = 1; i < 8; ++i) e = useMax ? fmaxf(e, acc[i][j]) : fminf(e, acc[i][j]);
      plex[tr * 64 + tc*4 + j] = e;
    }
    __syncthreads();                       // plex complete (all gemms of this half done)
    {
      const int pl = t >> 6, o = t & 63;   // 4 pairs x 64 channels
      const bool useMax = sg[h*64 + o] >= 0.0f;
      float e = plex[(pl*4 + 0) * 64 + o];
      #pragma unroll
      for (int i = 1; i < 4; ++i) {
        float v = plex[(pl*4 + i) * 64 + o];
        e = useMax ? fmaxf(e, v) : fminf(e, v);
      }
      out[OUT_NP_OFF + (size_t)(bp4 + pl) * 128 + h*64 + o] = e;
    }
    // next-half load_W is gated by the top-of-loop __syncthreads
  }
  __syncthreads();
  if (t < 128) { atomicAdd(&stats[256 + t], ssum[t]); atomicAdd(&stats[384 + t], ssq[t]); }
}

// ---------------- final: BN2+ReLU applied in place to pooled extrema ----------------
__global__ __launch_bounds__(256) void k_final(const float* __restrict__ stats,
                                               const float* __restrict__ g2,
                                               const float* __restrict__ bt2,
                                               float* __restrict__ out) {
  const int gid = blockIdx.x * 256 + threadIdx.x;   // < 2097152
  const int o = gid & 127;
  const float inv = 1.0f / CNT_TOTAL;
  float mu = stats[256 + o] * inv;
  float var = fmaxf(stats[384 + o] * inv - mu * mu, 0.0f);
  float rs = rsqrtf(var + 1e-5f);
  float s = g2[o] * rs;
  float b = bt2[o] - mu * s;
  float v = out[OUT_NP_OFF + gid];
  out[OUT_NP_OFF + gid] = fmaxf(fmaf(s, v, b), 0.0f);   // monotone BN+ReLU commutes with pool
}

extern "C" void kernel_launch(void* const* d_in, const int* in_sizes, int n_in,
                              void* d_out, int out_size, void* d_ws, size_t ws_size,
                              hipStream_t stream) {
  (void)in_sizes; (void)n_in; (void)out_size;
  const float* xyz    = (const float*)d_in[0];
  const float* points = (const float*)d_in[1];
  const float* W0  = (const float*)d_in[2];
  const float* b0  = (const float*)d_in[3];
  const float* g0  = (const float*)d_in[4];
  const float* bt0 = (const float*)d_in[5];
  const float* W1  = (const float*)d_in[6];
  const float* b1  = (const float*)d_in[7];
  const float* g1  = (const float*)d_in[8];
  const float* bt1 = (const float*)d_in[9];
  const float* W2  = (const float*)d_in[10];
  const float* b2  = (const float*)d_in[11];
  const float* g2  = (const float*)d_in[12];
  const float* bt2 = (const float*)d_in[13];
  float* out = (float*)d_out;

  // Workspace: stats 2 KB + ballidx 1 MB mandatory; ONE y buffer (f32, 134 MB) if room.
  // In-place ping: pass1 reads y rows (L0 pre-BN) and overwrites them with L1 pre-BN.
  const size_t statsB = 2048;
  const size_t ballB  = (size_t)16384 * NK * 2;       // 1,048,576
  const size_t MINWS  = statsB + ballB;               // 1,050,624
  const size_t yB     = (size_t)524288 * 64 * 4;      // 134,217,728

  char* ws = (char*)d_ws;
  float* stats      = (float*)ws;
  ushort_t* ballidx = (ushort_t*)(ws + statsB);
  float* ybuf       = (float*)(ws + MINWS);

  hipMemsetAsync(stats, 0, statsB, stream);
  k_fps <<<dim3(NB),   dim3(256),  0, stream>>>(xyz, out);
  k_ball<<<dim3(4096), dim3(256),  0, stream>>>(xyz, out, ballidx);

  if (ws_size >= MINWS + yB) {
    k_pass0<true>        <<<dim3(4096), dim3(256), 0, stream>>>(xyz, points, out, ballidx, W0, b0, ybuf, stats);
    k_pass1<true, true>  <<<dim3(4096), dim3(256), 0, stream>>>(xyz, points, out, ballidx, W0, b0, g0, bt0, W1, b1, ybuf, ybuf, stats);
    k_pass2<0>           <<<dim3(4096), dim3(256), 0, stream>>>(xyz, points, out, ballidx, W0, b0, g0, bt0, W1, b1, g1, bt1, W2, b2, g2, ybuf, out, stats);
  } else {
    k_pass0<false>       <<<dim3(4096), dim3(256), 0, stream>>>(xyz, points, out, ballidx, W0, b0, ybuf, stats);
    k_pass1<false, false><<<dim3(4096), dim3(256), 0, stream>>>(xyz, points, out, ballidx, W0, b0, g0, bt0, W1, b1, ybuf, ybuf, stats);
    k_pass2<2>           <<<dim3(4096), dim3(256), 0, stream>>>(xyz, points, out, ballidx, W0, b0, g0, bt0, W1, b1, g1, bt1, W2, b2, g2, ybuf, out, stats);
  }
  k_final<<<dim3(8192), dim3(256), 0, stream>>>(stats, g2, bt2, out);
}